// Round 3
// baseline (24706.654 us; speedup 1.0000x reference)
//
#include <hip/hip_runtime.h>
#include <hip/hip_bf16.h>

// ---------------- constants ----------------
#define BB   64     // batch
#define TT   200    // decoder steps
#define TE   512    // encoder positions
#define DD   256    // encoder dim / hidden
#define HH   256    // hidden
#define GG   768    // 3*H gates
#define INW  400    // mel in/out width
#define PN1  256
#define PN2  128
#define GBLK 128    // persistent grid blocks
#define CSC  2.8853900817779268f   // 2*log2(e) for tanh via exp2
#define L2E  1.4426950408889634f

typedef unsigned short ushortT;

__device__ __forceinline__ float blo(unsigned u) { return __uint_as_float(u << 16); }
__device__ __forceinline__ float bhi(unsigned u) { return __uint_as_float(u & 0xffff0000u); }

__device__ __forceinline__ float sigmf_(float x) {
    return __builtin_amdgcn_rcpf(1.f + __builtin_amdgcn_exp2f(-L2E * x));
}
__device__ __forceinline__ float tanhf_(float x) {
    // 1 - 2/(exp2(CSC*x)+1); overflow-safe: +inf->1, 0->-1
    return 1.f - 2.f * __builtin_amdgcn_rcpf(__builtin_amdgcn_exp2f(CSC * x) + 1.f);
}
__device__ __forceinline__ float gru_h(float ir, float iz, float in_, float hr, float hz,
                                       float hn, float hp) {
    float r = sigmf_(ir + hr), z = sigmf_(iz + hz);
    float n = tanhf_(in_ + r * hn);
    return (1.f - z) * n + z * hp;
}

#define FMA4(acc, w4, x0, x1, x2, x3) \
    acc = fmaf(x0, w4.x, acc); acc = fmaf(x1, w4.y, acc); \
    acc = fmaf(x2, w4.z, acc); acc = fmaf(x3, w4.w, acc)

// ---------------- generic tiled fp32 GEMM (precompute only) ----------------
// AMODE: 0 normal, 1 shifted-mel. SMODE: 0 fp32 rm; 1 xgi remap; 2 bf16 rm; 3 fp32 transposed
template<int AMODE, int SMODE, bool RELU, bool BIAS>
__global__ __launch_bounds__(256) void gemm_k(
    const float* __restrict__ A, const float* __restrict__ Bm,
    const float* __restrict__ bias, void* __restrict__ Cp,
    int M, int N, int K, int lda, int ldb)
{
    __shared__ __align__(16) float As[16][68];
    __shared__ __align__(16) float Bs[16][68];
    int tid = threadIdx.x;
    int m0 = blockIdx.y * 64, n0 = blockIdx.x * 64;
    int tx = tid & 15, ty = tid >> 4;
    float acc[4][4] = {};
    for (int k0 = 0; k0 < K; k0 += 16) {
        {
            int row = tid >> 2, kq = tid & 3;
            int gr = m0 + row;
            float4 a4;
            if (AMODE == 0) {
                a4 = *(const float4*)(A + (size_t)gr * lda + k0 + kq * 4);
            } else {
                int bb = gr / TT, t = gr % TT;
                if (t == 0) a4 = make_float4(0.f, 0.f, 0.f, 0.f);
                else a4 = *(const float4*)(A + ((size_t)bb * TT + (t - 1)) * INW + k0 + kq * 4);
            }
            As[kq * 4 + 0][row] = a4.x; As[kq * 4 + 1][row] = a4.y;
            As[kq * 4 + 2][row] = a4.z; As[kq * 4 + 3][row] = a4.w;
            int kk = tid >> 4, nq = tid & 15;
            int gc = n0 + nq * 4;
            float4 b4;
            if (gc + 3 < N) {
                b4 = *(const float4*)(Bm + (size_t)(k0 + kk) * ldb + gc);
            } else {
                b4.x = (gc + 0 < N) ? Bm[(size_t)(k0 + kk) * ldb + gc + 0] : 0.f;
                b4.y = (gc + 1 < N) ? Bm[(size_t)(k0 + kk) * ldb + gc + 1] : 0.f;
                b4.z = (gc + 2 < N) ? Bm[(size_t)(k0 + kk) * ldb + gc + 2] : 0.f;
                b4.w = (gc + 3 < N) ? Bm[(size_t)(k0 + kk) * ldb + gc + 3] : 0.f;
            }
            *(float4*)&Bs[kk][nq * 4] = b4;
        }
        __syncthreads();
#pragma unroll
        for (int kk = 0; kk < 16; ++kk) {
            float4 av = *(const float4*)&As[kk][ty * 4];
            float4 bv = *(const float4*)&Bs[kk][tx * 4];
            acc[0][0] = fmaf(av.x, bv.x, acc[0][0]); acc[0][1] = fmaf(av.x, bv.y, acc[0][1]);
            acc[0][2] = fmaf(av.x, bv.z, acc[0][2]); acc[0][3] = fmaf(av.x, bv.w, acc[0][3]);
            acc[1][0] = fmaf(av.y, bv.x, acc[1][0]); acc[1][1] = fmaf(av.y, bv.y, acc[1][1]);
            acc[1][2] = fmaf(av.y, bv.z, acc[1][2]); acc[1][3] = fmaf(av.y, bv.w, acc[1][3]);
            acc[2][0] = fmaf(av.z, bv.x, acc[2][0]); acc[2][1] = fmaf(av.z, bv.y, acc[2][1]);
            acc[2][2] = fmaf(av.z, bv.z, acc[2][2]); acc[2][3] = fmaf(av.z, bv.w, acc[2][3]);
            acc[3][0] = fmaf(av.w, bv.x, acc[3][0]); acc[3][1] = fmaf(av.w, bv.y, acc[3][1]);
            acc[3][2] = fmaf(av.w, bv.z, acc[3][2]); acc[3][3] = fmaf(av.w, bv.w, acc[3][3]);
        }
        __syncthreads();
    }
#pragma unroll
    for (int i = 0; i < 4; ++i) {
#pragma unroll
        for (int j = 0; j < 4; ++j) {
            int r = m0 + ty * 4 + i, c = n0 + tx * 4 + j;
            if (c >= N) continue;
            float v = acc[i][j];
            if (BIAS) v += bias[c];
            if (RELU) v = fmaxf(v, 0.f);
            if (SMODE == 0) ((float*)Cp)[(size_t)r * N + c] = v;
            else if (SMODE == 1) ((float*)Cp)[((size_t)(r % TT) * GG + c) * 64 + (r / TT)] = v;
            else if (SMODE == 2) ((__hip_bfloat16*)Cp)[(size_t)r * N + c] = __float2bfloat16(v);
            else ((float*)Cp)[(size_t)c * M + r] = v;
        }
    }
}

// ---------------- small precompute kernels ----------------
template<bool BF16>
__global__ __launch_bounds__(256) void trans_k(const float* __restrict__ in, int IR, int IC,
                                               int rowoff, void* __restrict__ out)
{
    int idx = blockIdx.x * 256 + threadIdx.x;
    if (idx >= IR * IC) return;
    int c = idx / IR, r = idx % IR;
    float v = in[(size_t)(r + rowoff) * IC + c];
    if (BF16) ((__hip_bfloat16*)out)[idx] = __float2bfloat16(v);
    else ((float*)out)[idx] = v;
}

__global__ __launch_bounds__(256) void scale_k(const float* __restrict__ in,
                                               float* __restrict__ out, int n, float s)
{
    int i = blockIdx.x * 256 + threadIdx.x;
    if (i < n) out[i] = in[i] * s;
}

__global__ __launch_bounds__(256) void vprep_k(const float* __restrict__ v,
                                               float* __restrict__ vn2)
{
    int i = threadIdx.x;
    if (i < 256) vn2[i] = -2.f * v[i];
}

// out[c] = bih[c] + sum_j projb[j] * W[j*N + c]
__global__ __launch_bounds__(256) void bfuse_k(const float* __restrict__ bih,
                                               const float* __restrict__ projb,
                                               const float* __restrict__ W, int N,
                                               float* __restrict__ out)
{
    int c = blockIdx.x * 256 + threadIdx.x;
    if (c >= N) return;
    float s = bih[c];
    for (int j = 0; j < 256; ++j) s = fmaf(projb[j], W[(size_t)j * N + c], s);
    out[c] = s;
}

// enc [b][p][d] fp32 -> encT [b][d][p] bf16, LDS-tiled
__global__ __launch_bounds__(256) void enct_k(const float* __restrict__ enc,
                                              ushortT* __restrict__ encT)
{
    int bid = blockIdx.x;
    int b = bid >> 6, pt = (bid >> 3) & 7, dt = bid & 7;
    int p0 = pt * 64, d0 = dt * 32;
    __shared__ ushortT tl[64][34];
    int tid = threadIdx.x;
    for (int i = tid; i < 64 * 32; i += 256) {
        int dd = i & 31, pp = i >> 5;
        float v = enc[((size_t)b * TE + p0 + pp) * DD + d0 + dd];
        tl[pp][dd] = (ushortT)(__bfloat16_as_ushort(__float2bfloat16(v)));
    }
    __syncthreads();
    for (int i = tid; i < 32 * 64; i += 256) {
        int pp = i & 63, dd = i >> 6;
        encT[((size_t)b * DD + d0 + dd) * TE + p0 + pp] = tl[pp][dd];
    }
}

// outsT [t][c][b] -> outs [b][t][c]
__global__ __launch_bounds__(256) void outtr_k(const float* __restrict__ outsT,
                                               float* __restrict__ outs)
{
    int bid = blockIdx.x;
    int t = bid / 7, ct = bid % 7;
    int c0 = ct * 64, cw = (ct == 6) ? (INW - 384) : 64;   // 16 or 64
    int cwl = (cw == 64) ? 6 : 4;
    __shared__ float tile[64][65];
    int tid = threadIdx.x;
    for (int i = tid; i < cw * 64; i += 256) {
        int ci = i >> 6, bb = i & 63;
        tile[ci][bb] = outsT[((size_t)t * INW + c0 + ci) * 64 + bb];
    }
    __syncthreads();
    for (int i = tid; i < 64 * cw; i += 256) {
        int bb = i >> cwl, cc = i & (cw - 1);
        outs[((size_t)bb * TT + t) * INW + c0 + cc] = tile[cc][bb];
    }
}

// ---------------- grid barrier ----------------
__device__ __forceinline__ void gridbar(unsigned* cnt, unsigned bar) {
    __syncthreads();
    if (threadIdx.x == 0) {
        __threadfence();
        __hip_atomic_fetch_add(cnt, 1u, __ATOMIC_RELAXED, __HIP_MEMORY_SCOPE_AGENT);
        unsigned target = bar * (unsigned)GBLK;
        while (__hip_atomic_load(cnt, __ATOMIC_RELAXED, __HIP_MEMORY_SCOPE_AGENT) < target) {
            __builtin_amdgcn_s_sleep(1);
        }
        __threadfence();
    }
    __syncthreads();
}

__device__ __forceinline__ float tpair(unsigned u32, int d, const float* qk,
                                       const float* vn2, float acc) {
    float xa = blo(u32) + qk[d];
    float xb = bhi(u32) + qk[d + 1];
    float ra = __builtin_amdgcn_rcpf(__builtin_amdgcn_exp2f(xa) + 1.f);
    float rb = __builtin_amdgcn_rcpf(__builtin_amdgcn_exp2f(xb) + 1.f);
    acc = fmaf(vn2[d], ra, acc);
    return fmaf(vn2[d + 1], rb, acc);
}

// ---------------- persistent mega kernel ----------------
__global__ __launch_bounds__(512, 2) void mega_k(
    const float* __restrict__ xgi, const float* __restrict__ WihcT,
    const float* __restrict__ WhhT, const float* __restrict__ att_bhh,
    const float* __restrict__ F1T, const float* __restrict__ Whh1T,
    const float* __restrict__ bf1, const float* __restrict__ d1_bhh,
    const float* __restrict__ F2T, const float* __restrict__ Wih2T,
    const float* __restrict__ Whh2T, const float* __restrict__ b2c,
    const float* __restrict__ d2_bhh,
    const float* __restrict__ melT, const float* __restrict__ FMT,
    const float* __restrict__ bmc,
    const ushortT* __restrict__ WqT, const ushortT* __restrict__ pmB,
    const ushortT* __restrict__ encT, const float* __restrict__ vn2g,
    float* __restrict__ states, float* __restrict__ outsT,
    float* __restrict__ aligns, unsigned* __restrict__ cnt)
{
    const int tid = threadIdx.x, bid = blockIdx.x;
    const int lane = tid & 63, wq = tid >> 6;
    __shared__ __align__(16) float smem[2600];
    float* part = smem;   // [8][3][64]
    unsigned bar = 0;
    const size_t SB = (size_t)HH * BB;
    float* attH = states;
    float* ctxS = states + 2 * SB;
    float* h1S  = states + 4 * SB;
    float* h2S  = states + 6 * SB;

#define PPART(q, g) part[((q) * 3 + (g)) * 64 + lane]

    for (int t = 0; t < TT; ++t) {
        const int cur = t & 1, nxt = cur ^ 1;
        const float* hC  = attH + cur * SB;  float* hN  = attH + nxt * SB;
        const float* cC  = ctxS + cur * SB;  float* cN  = ctxS + nxt * SB;
        const float* h1C = h1S + cur * SB;   float* h1N = h1S + nxt * SB;
        const float* h2C = h2S + cur * SB;   float* h2N = h2S + nxt * SB;
        const float* xgi_t = xgi + (size_t)t * (GG * 64);

        // ===== phase 1: attention GRU (all blocks, 2 units each) =====
        {
            int ul = wq & 1, kh = (wq >> 1) & 1, role = wq >> 2;
            int u = bid * 2 + ul;
            const float* W  = role ? WhhT : WihcT;
            const float* st = (role ? hC : cC) + kh * 128 * 64 + lane;
            const float* w0 = W + ((size_t)u) * 256 + kh * 128;
            const float* w1 = W + ((size_t)(256 + u)) * 256 + kh * 128;
            const float* w2 = W + ((size_t)(512 + u)) * 256 + kh * 128;
            float s0 = 0.f, s1 = 0.f, s2 = 0.f;
            for (int j = 0; j < 128; j += 4) {
                float4 a0 = *(const float4*)(w0 + j);
                float4 a1 = *(const float4*)(w1 + j);
                float4 a2 = *(const float4*)(w2 + j);
                float x0 = st[(j + 0) * 64], x1 = st[(j + 1) * 64];
                float x2 = st[(j + 2) * 64], x3 = st[(j + 3) * 64];
                FMA4(s0, a0, x0, x1, x2, x3);
                FMA4(s1, a1, x0, x1, x2, x3);
                FMA4(s2, a2, x0, x1, x2, x3);
            }
            PPART(wq, 0) = s0; PPART(wq, 1) = s1; PPART(wq, 2) = s2;
            __syncthreads();
            if (wq < 2) {
                int uu = bid * 2 + wq;
                float ir  = PPART(wq, 0) + PPART(wq + 2, 0) + xgi_t[(size_t)uu * 64 + lane];
                float iz  = PPART(wq, 1) + PPART(wq + 2, 1) + xgi_t[(size_t)(256 + uu) * 64 + lane];
                float in_ = PPART(wq, 2) + PPART(wq + 2, 2) + xgi_t[(size_t)(512 + uu) * 64 + lane];
                float hr  = PPART(wq + 4, 0) + PPART(wq + 6, 0) + att_bhh[uu];
                float hz  = PPART(wq + 4, 1) + PPART(wq + 6, 1) + att_bhh[256 + uu];
                float hn  = PPART(wq + 4, 2) + PPART(wq + 6, 2) + att_bhh[512 + uu];
                float hp  = hC[(size_t)uu * 64 + lane];
                hN[(size_t)uu * 64 + lane] = gru_h(ir, iz, in_, hr, hz, hn, hp);
            }
        }
        gridbar(cnt, ++bar);

        // ===== phase 2: attention (blocks 0..63, one per batch) =====
        if (bid < BB) {
            const int b = bid;
            float* hsh   = smem;            // 256
            float* qk    = smem + 256;      // 256
            float* vn2   = smem + 512;      // 256
            float* ash   = smem + 768;      // 512
            float* red   = smem + 1280;     // 16
            float* cpart = smem + 1312;     // 512
            if (tid < 256) { hsh[tid] = hN[(size_t)tid * 64 + b]; vn2[tid] = vn2g[tid]; }
            __syncthreads();
            if (tid < 256) {
                const ushortT* wr = WqT + (size_t)tid * 256;
                float acc = 0.f;
                for (int k = 0; k < 256; k += 8) {
                    uint4 w = *(const uint4*)(wr + k);
                    acc = fmaf(hsh[k + 0], blo(w.x), acc); acc = fmaf(hsh[k + 1], bhi(w.x), acc);
                    acc = fmaf(hsh[k + 2], blo(w.y), acc); acc = fmaf(hsh[k + 3], bhi(w.y), acc);
                    acc = fmaf(hsh[k + 4], blo(w.z), acc); acc = fmaf(hsh[k + 5], bhi(w.z), acc);
                    acc = fmaf(hsh[k + 6], blo(w.w), acc); acc = fmaf(hsh[k + 7], bhi(w.w), acc);
                }
                qk[tid] = acc * CSC;
            }
            __syncthreads();
            // scores: one position per thread
            const ushortT* pr = pmB + ((size_t)b * TE + tid) * 256;
            float e = 0.f;
            for (int d = 0; d < 256; d += 8) {
                uint4 w = *(const uint4*)(pr + d);
                e = tpair(w.x, d + 0, qk, vn2, e);
                e = tpair(w.y, d + 2, qk, vn2, e);
                e = tpair(w.z, d + 4, qk, vn2, e);
                e = tpair(w.w, d + 6, qk, vn2, e);
            }
            float m = e;
            for (int o = 32; o; o >>= 1) m = fmaxf(m, __shfl_xor(m, o));
            if (lane == 0) red[wq] = m;
            __syncthreads();
            m = red[0];
            for (int i = 1; i < 8; ++i) m = fmaxf(m, red[i]);
            float pe = __builtin_amdgcn_exp2f((e - m) * L2E);
            float ssum = pe;
            for (int o = 32; o; o >>= 1) ssum += __shfl_xor(ssum, o);
            __syncthreads();
            if (lane == 0) red[wq] = ssum;
            __syncthreads();
            ssum = red[0] + red[1] + red[2] + red[3] + red[4] + red[5] + red[6] + red[7];
            float a = pe * __builtin_amdgcn_rcpf(ssum);
            ash[tid] = a;
            aligns[((size_t)b * TT + t) * TE + tid] = a;
            __syncthreads();
            // ctx
            int d = tid & 255, ph = tid >> 8;
            const ushortT* er = encT + ((size_t)(b * DD + d)) * TE + ph * 256;
            const float* ap = ash + ph * 256;
            float acc = 0.f;
            for (int p = 0; p < 256; p += 8) {
                uint4 w = *(const uint4*)(er + p);
                acc = fmaf(ap[p + 0], blo(w.x), acc); acc = fmaf(ap[p + 1], bhi(w.x), acc);
                acc = fmaf(ap[p + 2], blo(w.y), acc); acc = fmaf(ap[p + 3], bhi(w.y), acc);
                acc = fmaf(ap[p + 4], blo(w.z), acc); acc = fmaf(ap[p + 5], bhi(w.z), acc);
                acc = fmaf(ap[p + 6], blo(w.w), acc); acc = fmaf(ap[p + 7], bhi(w.w), acc);
            }
            cpart[ph * 256 + d] = acc;
            __syncthreads();
            if (tid < 256) cN[(size_t)tid * 64 + b] = cpart[tid] + cpart[256 + tid];
        }
        gridbar(cnt, ++bar);

        // ===== phase 4: dec1 GRU (all blocks, 2 units each) =====
        {
            int ul = wq & 1, sub = wq >> 1;
            int u = bid * 2 + ul;
            float s0 = 0.f, s1 = 0.f, s2 = 0.f;
            if (sub < 2) {
                const float* st = (sub ? cN : hN) + lane;
                const float* w0 = F1T + ((size_t)u) * 512 + sub * 256;
                const float* w1 = F1T + ((size_t)(256 + u)) * 512 + sub * 256;
                const float* w2 = F1T + ((size_t)(512 + u)) * 512 + sub * 256;
                for (int j = 0; j < 256; j += 4) {
                    float4 a0 = *(const float4*)(w0 + j);
                    float4 a1 = *(const float4*)(w1 + j);
                    float4 a2 = *(const float4*)(w2 + j);
                    float x0 = st[(j + 0) * 64], x1 = st[(j + 1) * 64];
                    float x2 = st[(j + 2) * 64], x3 = st[(j + 3) * 64];
                    FMA4(s0, a0, x0, x1, x2, x3);
                    FMA4(s1, a1, x0, x1, x2, x3);
                    FMA4(s2, a2, x0, x1, x2, x3);
                }
            } else {
                int kh = sub - 2;
                const float* st = h1C + kh * 128 * 64 + lane;
                const float* w0 = Whh1T + ((size_t)u) * 256 + kh * 128;
                const float* w1 = Whh1T + ((size_t)(256 + u)) * 256 + kh * 128;
                const float* w2 = Whh1T + ((size_t)(512 + u)) * 256 + kh * 128;
                for (int j = 0; j < 128; j += 4) {
                    float4 a0 = *(const float4*)(w0 + j);
                    float4 a1 = *(const float4*)(w1 + j);
                    float4 a2 = *(const float4*)(w2 + j);
                    float x0 = st[(j + 0) * 64], x1 = st[(j + 1) * 64];
                    float x2 = st[(j + 2) * 64], x3 = st[(j + 3) * 64];
                    FMA4(s0, a0, x0, x1, x2, x3);
                    FMA4(s1, a1, x0, x1, x2, x3);
                    FMA4(s2, a2, x0, x1, x2, x3);
                }
            }
            PPART(wq, 0) = s0; PPART(wq, 1) = s1; PPART(wq, 2) = s2;
            __syncthreads();
            if (wq < 2) {
                int uu = bid * 2 + wq;
                float ir  = PPART(wq, 0) + PPART(wq + 2, 0) + bf1[uu];
                float iz  = PPART(wq, 1) + PPART(wq + 2, 1) + bf1[256 + uu];
                float in_ = PPART(wq, 2) + PPART(wq + 2, 2) + bf1[512 + uu];
                float hr  = PPART(wq + 4, 0) + PPART(wq + 6, 0) + d1_bhh[uu];
                float hz  = PPART(wq + 4, 1) + PPART(wq + 6, 1) + d1_bhh[256 + uu];
                float hn  = PPART(wq + 4, 2) + PPART(wq + 6, 2) + d1_bhh[512 + uu];
                float hp  = h1C[(size_t)uu * 64 + lane];
                h1N[(size_t)uu * 64 + lane] = gru_h(ir, iz, in_, hr, hz, hn, hp);
            }
        }
        gridbar(cnt, ++bar);

        // ===== phase 5: dec2 GRU (all blocks, 2 units each) =====
        {
            int ul = wq & 1, sub = wq >> 1;
            int u = bid * 2 + ul;
            float s0 = 0.f, s1 = 0.f, s2 = 0.f;
            const float* st; const float* w0; const float* w1; const float* w2;
            if (sub == 0) {
                st = hN + lane;
                w0 = F2T + ((size_t)u) * 512;
                w1 = F2T + ((size_t)(256 + u)) * 512;
                w2 = F2T + ((size_t)(512 + u)) * 512;
            } else if (sub == 1) {
                st = cN + lane;
                w0 = F2T + ((size_t)u) * 512 + 256;
                w1 = F2T + ((size_t)(256 + u)) * 512 + 256;
                w2 = F2T + ((size_t)(512 + u)) * 512 + 256;
            } else if (sub == 2) {
                st = h1N + lane;
                w0 = Wih2T + ((size_t)u) * 256;
                w1 = Wih2T + ((size_t)(256 + u)) * 256;
                w2 = Wih2T + ((size_t)(512 + u)) * 256;
            } else {
                st = h2C + lane;
                w0 = Whh2T + ((size_t)u) * 256;
                w1 = Whh2T + ((size_t)(256 + u)) * 256;
                w2 = Whh2T + ((size_t)(512 + u)) * 256;
            }
            for (int j = 0; j < 256; j += 4) {
                float4 a0 = *(const float4*)(w0 + j);
                float4 a1 = *(const float4*)(w1 + j);
                float4 a2 = *(const float4*)(w2 + j);
                float x0 = st[(j + 0) * 64], x1 = st[(j + 1) * 64];
                float x2 = st[(j + 2) * 64], x3 = st[(j + 3) * 64];
                FMA4(s0, a0, x0, x1, x2, x3);
                FMA4(s1, a1, x0, x1, x2, x3);
                FMA4(s2, a2, x0, x1, x2, x3);
            }
            PPART(wq, 0) = s0; PPART(wq, 1) = s1; PPART(wq, 2) = s2;
            __syncthreads();
            if (wq < 2) {
                int uu = bid * 2 + wq;
                float ir  = PPART(wq, 0) + PPART(wq + 2, 0) + PPART(wq + 4, 0) + b2c[uu];
                float iz  = PPART(wq, 1) + PPART(wq + 2, 1) + PPART(wq + 4, 1) + b2c[256 + uu];
                float in_ = PPART(wq, 2) + PPART(wq + 2, 2) + PPART(wq + 4, 2) + b2c[512 + uu];
                float hr  = PPART(wq + 6, 0) + d2_bhh[uu];
                float hz  = PPART(wq + 6, 1) + d2_bhh[256 + uu];
                float hn  = PPART(wq + 6, 2) + d2_bhh[512 + uu];
                float hp  = h2C[(size_t)uu * 64 + lane];
                h2N[(size_t)uu * 64 + lane] = gru_h(ir, iz, in_, hr, hz, hn, hp);
            }
        }
        gridbar(cnt, ++bar);

        // ===== phase 6: mel out (blocks 0..99, 4 cols each) =====
        if (bid < 100) {
            int colq = wq & 3, kh = wq >> 2;
            int c = bid * 4 + colq;
            float acc = 0.f;
            if (kh == 0) {
                acc = bmc[c];
                const float* w = melT + (size_t)c * 256;
                for (int j = 0; j < 256; j += 4) {
                    float4 w4 = *(const float4*)(w + j);
                    float x0 = h1N[(size_t)(j + 0) * 64 + lane] + h2N[(size_t)(j + 0) * 64 + lane];
                    float x1 = h1N[(size_t)(j + 1) * 64 + lane] + h2N[(size_t)(j + 1) * 64 + lane];
                    float x2 = h1N[(size_t)(j + 2) * 64 + lane] + h2N[(size_t)(j + 2) * 64 + lane];
                    float x3 = h1N[(size_t)(j + 3) * 64 + lane] + h2N[(size_t)(j + 3) * 64 + lane];
                    FMA4(acc, w4, x0, x1, x2, x3);
                }
                const float* f = FMT + (size_t)c * 512;
                for (int j = 0; j < 128; j += 4) {
                    float4 f4 = *(const float4*)(f + j);
                    float x0 = hN[(size_t)(j + 0) * 64 + lane], x1 = hN[(size_t)(j + 1) * 64 + lane];
                    float x2 = hN[(size_t)(j + 2) * 64 + lane], x3 = hN[(size_t)(j + 3) * 64 + lane];
                    FMA4(acc, f4, x0, x1, x2, x3);
                }
            } else {
                const float* f = FMT + (size_t)c * 512 + 128;
                for (int j = 0; j < 128; j += 4) {
                    float4 f4 = *(const float4*)(f + j);
                    float x0 = hN[(size_t)(128 + j + 0) * 64 + lane], x1 = hN[(size_t)(128 + j + 1) * 64 + lane];
                    float x2 = hN[(size_t)(128 + j + 2) * 64 + lane], x3 = hN[(size_t)(128 + j + 3) * 64 + lane];
                    FMA4(acc, f4, x0, x1, x2, x3);
                }
                const float* f2 = FMT + (size_t)c * 512 + 256;
                for (int j = 0; j < 256; j += 4) {
                    float4 f4 = *(const float4*)(f2 + j);
                    float x0 = cN[(size_t)(j + 0) * 64 + lane], x1 = cN[(size_t)(j + 1) * 64 + lane];
                    float x2 = cN[(size_t)(j + 2) * 64 + lane], x3 = cN[(size_t)(j + 3) * 64 + lane];
                    FMA4(acc, f4, x0, x1, x2, x3);
                }
                smem[wq * 64 + lane] = acc;
            }
            __syncthreads();
            if (kh == 0)
                outsT[((size_t)t * INW + c) * 64 + lane] = acc + smem[(wq + 4) * 64 + lane];
        }
        __syncthreads();
    }
#undef PPART
}

// ---------------- host launcher ----------------
extern "C" void kernel_launch(void* const* d_in, const int* in_sizes, int n_in,
                              void* d_out, int out_size, void* d_ws, size_t ws_size,
                              hipStream_t stream) {
    const float* enc     = (const float*)d_in[0];
    const float* mel     = (const float*)d_in[1];
    const float* pw1     = (const float*)d_in[2];
    const float* pb1     = (const float*)d_in[3];
    const float* pw2     = (const float*)d_in[4];
    const float* pb2     = (const float*)d_in[5];
    const float* att_wih = (const float*)d_in[6];
    const float* att_whh = (const float*)d_in[7];
    const float* att_bih = (const float*)d_in[8];
    const float* att_bhh = (const float*)d_in[9];
    const float* mem_w   = (const float*)d_in[10];
    const float* query_w = (const float*)d_in[11];
    const float* att_v   = (const float*)d_in[12];
    const float* proj_w  = (const float*)d_in[13];
    const float* proj_b  = (const float*)d_in[14];
    const float* d1_wih  = (const float*)d_in[15];
    const float* d1_whh  = (const float*)d_in[16];
    const float* d1_bih  = (const float*)d_in[17];
    const float* d1_bhh  = (const float*)d_in[18];
    const float* d2_wih  = (const float*)d_in[19];
    const float* d2_whh  = (const float*)d_in[20];
    const float* d2_bih  = (const float*)d_in[21];
    const float* d2_bhh  = (const float*)d_in[22];
    const float* mel_w   = (const float*)d_in[23];
    const float* mel_b   = (const float*)d_in[24];

    float* outs = (float*)d_out;
    float* aligns = outs + (size_t)BB * TT * INW;

    char* p = (char*)d_ws;
    auto take = [&](size_t bytes) -> char* {
        char* r = p;
        p += (bytes + 255) & ~(size_t)255;
        return r;
    };
    const size_t SB = (size_t)HH * BB;
    float* states = (float*)take(8 * SB * 4);
    unsigned* cnt = (unsigned*)take(256);
    // union region: X1(13.1MB)+X2(6.6MB) during precompute, outsT(20.5MB) during mega
    char* bufA = take((size_t)TT * INW * 64 * 4);   // 20.48MB
    float* X1 = (float*)bufA;
    float* X2 = (float*)(bufA + (size_t)BB * TT * PN1 * 4);
    float* outsT = (float*)bufA;
    float* xgi = (float*)take((size_t)TT * GG * BB * 4);
    __hip_bfloat16* pmB  = (__hip_bfloat16*)take((size_t)BB * TE * DD * 2);
    ushortT* encT = (ushortT*)take((size_t)BB * TE * DD * 2);
    float* WihcT = (float*)take((size_t)GG * 256 * 4);
    float* WhhT  = (float*)take((size_t)GG * 256 * 4);
    float* Whh1T = (float*)take((size_t)GG * 256 * 4);
    float* Whh2T = (float*)take((size_t)GG * 256 * 4);
    float* Wih2T = (float*)take((size_t)GG * 256 * 4);
    float* melT  = (float*)take((size_t)INW * 256 * 4);
    float* F1T   = (float*)take((size_t)GG * 512 * 4);
    float* F2T   = (float*)take((size_t)GG * 512 * 4);
    float* FMT   = (float*)take((size_t)INW * 512 * 4);
    __hip_bfloat16* WqT = (__hip_bfloat16*)take((size_t)256 * 256 * 2);
    float* memwS = (float*)take((size_t)DD * 256 * 4);
    float* bf1 = (float*)take(GG * 4);
    float* b2c = (float*)take(GG * 4);
    float* bmc = (float*)take(INW * 4);
    float* vn2g = (float*)take(256 * 4);

    (void)hipMemsetAsync(states, 0, 8 * SB * 4, stream);
    (void)hipMemsetAsync(cnt, 0, 256, stream);

    // weight transposes / preps
    trans_k<false><<<(256 * GG + 255) / 256, 256, 0, stream>>>(att_wih, 256, GG, 128, WihcT);
    trans_k<false><<<(256 * GG + 255) / 256, 256, 0, stream>>>(att_whh, 256, GG, 0, WhhT);
    trans_k<false><<<(256 * GG + 255) / 256, 256, 0, stream>>>(d1_whh, 256, GG, 0, Whh1T);
    trans_k<false><<<(256 * GG + 255) / 256, 256, 0, stream>>>(d2_whh, 256, GG, 0, Whh2T);
    trans_k<false><<<(256 * GG + 255) / 256, 256, 0, stream>>>(d2_wih, 256, GG, 0, Wih2T);
    trans_k<false><<<(256 * INW + 255) / 256, 256, 0, stream>>>(mel_w, 256, INW, 0, melT);
    trans_k<true><<<(256 * 256 + 255) / 256, 256, 0, stream>>>(query_w, 256, 256, 0, WqT);
    scale_k<<<(DD * 256 + 255) / 256, 256, 0, stream>>>(mem_w, memwS, DD * 256, CSC);
    vprep_k<<<1, 256, 0, stream>>>(att_v, vn2g);
    enct_k<<<64 * 64, 256, 0, stream>>>(enc, encT);
    bfuse_k<<<3, 256, 0, stream>>>(d1_bih, proj_b, d1_wih, GG, bf1);
    bfuse_k<<<3, 256, 0, stream>>>(d2_bih, proj_b, d2_wih, GG, b2c);
    bfuse_k<<<2, 256, 0, stream>>>(mel_b, proj_b, mel_w, INW, bmc);

    // precompute GEMMs
    gemm_k<1, 0, true, true><<<dim3(PN1 / 64, BB * TT / 64), 256, 0, stream>>>(
        mel, pw1, pb1, X1, BB * TT, PN1, INW, INW, PN1);
    gemm_k<0, 0, true, true><<<dim3(PN2 / 64, BB * TT / 64), 256, 0, stream>>>(
        X1, pw2, pb2, X2, BB * TT, PN2, PN1, PN1, PN2);
    gemm_k<0, 1, false, true><<<dim3(GG / 64, BB * TT / 64), 256, 0, stream>>>(
        X2, att_wih, att_bih, xgi, BB * TT, GG, PN2, PN2, GG);
    gemm_k<0, 2, false, false><<<dim3(DD / 64, BB * TE / 64), 256, 0, stream>>>(
        enc, memwS, nullptr, pmB, BB * TE, DD, DD, DD, DD);
    gemm_k<0, 3, false, false><<<dim3(GG / 64, 512 / 64), 256, 0, stream>>>(
        proj_w, d1_wih, nullptr, F1T, 512, GG, 256, 256, GG);
    gemm_k<0, 3, false, false><<<dim3(GG / 64, 512 / 64), 256, 0, stream>>>(
        proj_w, d2_wih, nullptr, F2T, 512, GG, 256, 256, GG);
    gemm_k<0, 3, false, false><<<dim3((INW + 63) / 64, 512 / 64), 256, 0, stream>>>(
        proj_w, mel_w, nullptr, FMT, 512, INW, 256, 256, INW);

    // the whole recurrence in one persistent kernel
    mega_k<<<GBLK, 512, 0, stream>>>(
        xgi, WihcT, WhhT, att_bhh,
        F1T, Whh1T, bf1, d1_bhh,
        F2T, Wih2T, Whh2T, b2c, d2_bhh,
        melT, FMT, bmc,
        (const ushortT*)WqT, (const ushortT*)pmB, encT, vn2g,
        states, outsT, aligns, cnt);

    // outsT [t][c][b] -> outs [b][t][c]
    outtr_k<<<TT * 7, 256, 0, stream>>>(outsT, outs);
}

// Round 4
// 19582.140 us; speedup vs baseline: 1.2617x; 1.2617x over previous
//
#include <hip/hip_runtime.h>
#include <hip/hip_bf16.h>

// ---------------- constants ----------------
#define BB   64     // batch
#define TT   200    // decoder steps
#define TE   512    // encoder positions
#define DD   256    // encoder dim / hidden
#define HH   256    // hidden
#define GG   768    // 3*H gates
#define INW  400    // mel in/out width
#define PN1  256
#define PN2  128
#define GBLK 128    // persistent grid blocks
#define NG   (TT + 2)   // state generations (gen g written at step t=g-2)
#define SBE  (HH * BB)  // one state gen, floats (16384 = 64KB)
#define CSC  2.8853900817779268f   // 2*log2(e) for tanh via exp2
#define L2E  1.4426950408889634f

typedef unsigned short ushortT;

__device__ __forceinline__ float blo(unsigned u) { return __uint_as_float(u << 16); }
__device__ __forceinline__ float bhi(unsigned u) { return __uint_as_float(u & 0xffff0000u); }
__device__ __forceinline__ float bf2f(ushortT u) { return __uint_as_float(((unsigned)u) << 16); }

__device__ __forceinline__ float sigmf_(float x) {
    return __builtin_amdgcn_rcpf(1.f + __builtin_amdgcn_exp2f(-L2E * x));
}
__device__ __forceinline__ float tanhf_(float x) {
    return 1.f - 2.f * __builtin_amdgcn_rcpf(__builtin_amdgcn_exp2f(CSC * x) + 1.f);
}
__device__ __forceinline__ float gru_h(float ir, float iz, float in_, float hr, float hz,
                                       float hn, float hp) {
    float r = sigmf_(ir + hr), z = sigmf_(iz + hz);
    float n = tanhf_(in_ + r * hn);
    return (1.f - z) * n + z * hp;
}

// state store: sc0+sc1 write-through to MALL (coherent point), bypasses L2 -> no stale dirty lines
__device__ __forceinline__ void stS(float* p, float v) {
    __hip_atomic_store(p, v, __ATOMIC_RELAXED, __HIP_MEMORY_SCOPE_AGENT);
}

#define FMA4(acc, w4, x0, x1, x2, x3) \
    acc = fmaf(x0, w4.x, acc); acc = fmaf(x1, w4.y, acc); \
    acc = fmaf(x2, w4.z, acc); acc = fmaf(x3, w4.w, acc)

// 6-stream matvec partial: states laid out [dim][64]
__device__ __forceinline__ void mv6(const float* __restrict__ st,
    const float* __restrict__ w0, const float* __restrict__ w1,
    const float* __restrict__ w2, const float* __restrict__ w3,
    const float* __restrict__ w4, const float* __restrict__ w5, int dims,
    float& a0, float& a1, float& a2, float& a3, float& a4, float& a5)
{
    for (int j = 0; j < dims; j += 4) {
        float x0 = st[(j + 0) * 64], x1 = st[(j + 1) * 64];
        float x2 = st[(j + 2) * 64], x3 = st[(j + 3) * 64];
        float4 w;
        w = *(const float4*)(w0 + j); FMA4(a0, w, x0, x1, x2, x3);
        w = *(const float4*)(w1 + j); FMA4(a1, w, x0, x1, x2, x3);
        w = *(const float4*)(w2 + j); FMA4(a2, w, x0, x1, x2, x3);
        w = *(const float4*)(w3 + j); FMA4(a3, w, x0, x1, x2, x3);
        w = *(const float4*)(w4 + j); FMA4(a4, w, x0, x1, x2, x3);
        w = *(const float4*)(w5 + j); FMA4(a5, w, x0, x1, x2, x3);
    }
}

__device__ __forceinline__ void mv4(const float* __restrict__ st,
    const float* __restrict__ w0, const float* __restrict__ w1,
    const float* __restrict__ w2, const float* __restrict__ w3, int dims,
    float& a0, float& a1, float& a2, float& a3)
{
    for (int j = 0; j < dims; j += 4) {
        float x0 = st[(j + 0) * 64], x1 = st[(j + 1) * 64];
        float x2 = st[(j + 2) * 64], x3 = st[(j + 3) * 64];
        float4 w;
        w = *(const float4*)(w0 + j); FMA4(a0, w, x0, x1, x2, x3);
        w = *(const float4*)(w1 + j); FMA4(a1, w, x0, x1, x2, x3);
        w = *(const float4*)(w2 + j); FMA4(a2, w, x0, x1, x2, x3);
        w = *(const float4*)(w3 + j); FMA4(a3, w, x0, x1, x2, x3);
    }
}

// ---------------- generic tiled fp32 GEMM (precompute only) ----------------
// AMODE: 0 normal, 1 shifted-mel. SMODE: 0 fp32 rm; 1 xgi remap (bf16!); 2 bf16 rm; 3 fp32 transposed
template<int AMODE, int SMODE, bool RELU, bool BIAS>
__global__ __launch_bounds__(256) void gemm_k(
    const float* __restrict__ A, const float* __restrict__ Bm,
    const float* __restrict__ bias, void* __restrict__ Cp,
    int M, int N, int K, int lda, int ldb)
{
    __shared__ __align__(16) float As[16][68];
    __shared__ __align__(16) float Bs[16][68];
    int tid = threadIdx.x;
    int m0 = blockIdx.y * 64, n0 = blockIdx.x * 64;
    int tx = tid & 15, ty = tid >> 4;
    float acc[4][4] = {};
    for (int k0 = 0; k0 < K; k0 += 16) {
        {
            int row = tid >> 2, kq = tid & 3;
            int gr = m0 + row;
            float4 a4;
            if (AMODE == 0) {
                a4 = *(const float4*)(A + (size_t)gr * lda + k0 + kq * 4);
            } else {
                int bb = gr / TT, t = gr % TT;
                if (t == 0) a4 = make_float4(0.f, 0.f, 0.f, 0.f);
                else a4 = *(const float4*)(A + ((size_t)bb * TT + (t - 1)) * INW + k0 + kq * 4);
            }
            As[kq * 4 + 0][row] = a4.x; As[kq * 4 + 1][row] = a4.y;
            As[kq * 4 + 2][row] = a4.z; As[kq * 4 + 3][row] = a4.w;
            int kk = tid >> 4, nq = tid & 15;
            int gc = n0 + nq * 4;
            float4 b4;
            if (gc + 3 < N) {
                b4 = *(const float4*)(Bm + (size_t)(k0 + kk) * ldb + gc);
            } else {
                b4.x = (gc + 0 < N) ? Bm[(size_t)(k0 + kk) * ldb + gc + 0] : 0.f;
                b4.y = (gc + 1 < N) ? Bm[(size_t)(k0 + kk) * ldb + gc + 1] : 0.f;
                b4.z = (gc + 2 < N) ? Bm[(size_t)(k0 + kk) * ldb + gc + 2] : 0.f;
                b4.w = (gc + 3 < N) ? Bm[(size_t)(k0 + kk) * ldb + gc + 3] : 0.f;
            }
            *(float4*)&Bs[kk][nq * 4] = b4;
        }
        __syncthreads();
#pragma unroll
        for (int kk = 0; kk < 16; ++kk) {
            float4 av = *(const float4*)&As[kk][ty * 4];
            float4 bv = *(const float4*)&Bs[kk][tx * 4];
            acc[0][0] = fmaf(av.x, bv.x, acc[0][0]); acc[0][1] = fmaf(av.x, bv.y, acc[0][1]);
            acc[0][2] = fmaf(av.x, bv.z, acc[0][2]); acc[0][3] = fmaf(av.x, bv.w, acc[0][3]);
            acc[1][0] = fmaf(av.y, bv.x, acc[1][0]); acc[1][1] = fmaf(av.y, bv.y, acc[1][1]);
            acc[1][2] = fmaf(av.y, bv.z, acc[1][2]); acc[1][3] = fmaf(av.y, bv.w, acc[1][3]);
            acc[2][0] = fmaf(av.z, bv.x, acc[2][0]); acc[2][1] = fmaf(av.z, bv.y, acc[2][1]);
            acc[2][2] = fmaf(av.z, bv.z, acc[2][2]); acc[2][3] = fmaf(av.z, bv.w, acc[2][3]);
            acc[3][0] = fmaf(av.w, bv.x, acc[3][0]); acc[3][1] = fmaf(av.w, bv.y, acc[3][1]);
            acc[3][2] = fmaf(av.w, bv.z, acc[3][2]); acc[3][3] = fmaf(av.w, bv.w, acc[3][3]);
        }
        __syncthreads();
    }
#pragma unroll
    for (int i = 0; i < 4; ++i) {
#pragma unroll
        for (int j = 0; j < 4; ++j) {
            int r = m0 + ty * 4 + i, c = n0 + tx * 4 + j;
            if (c >= N) continue;
            float v = acc[i][j];
            if (BIAS) v += bias[c];
            if (RELU) v = fmaxf(v, 0.f);
            if (SMODE == 0) ((float*)Cp)[(size_t)r * N + c] = v;
            else if (SMODE == 1) ((__hip_bfloat16*)Cp)[((size_t)(r % TT) * GG + c) * 64 + (r / TT)] = __float2bfloat16(v);
            else if (SMODE == 2) ((__hip_bfloat16*)Cp)[(size_t)r * N + c] = __float2bfloat16(v);
            else ((float*)Cp)[(size_t)c * M + r] = v;
        }
    }
}

// ---------------- small precompute kernels ----------------
template<bool BF16>
__global__ __launch_bounds__(256) void trans_k(const float* __restrict__ in, int IR, int IC,
                                               int rowoff, void* __restrict__ out)
{
    int idx = blockIdx.x * 256 + threadIdx.x;
    if (idx >= IR * IC) return;
    int c = idx / IR, r = idx % IR;
    float v = in[(size_t)(r + rowoff) * IC + c];
    if (BF16) ((__hip_bfloat16*)out)[idx] = __float2bfloat16(v);
    else ((float*)out)[idx] = v;
}

__global__ __launch_bounds__(256) void scale_k(const float* __restrict__ in,
                                               float* __restrict__ out, int n, float s)
{
    int i = blockIdx.x * 256 + threadIdx.x;
    if (i < n) out[i] = in[i] * s;
}

__global__ __launch_bounds__(256) void vprep_k(const float* __restrict__ v,
                                               float* __restrict__ vn2)
{
    int i = threadIdx.x;
    if (i < 256) vn2[i] = -2.f * v[i];
}

// out[c] = bih[c] + sum_j projb[j] * W[j*N + c]
__global__ __launch_bounds__(256) void bfuse_k(const float* __restrict__ bih,
                                               const float* __restrict__ projb,
                                               const float* __restrict__ W, int N,
                                               float* __restrict__ out)
{
    int c = blockIdx.x * 256 + threadIdx.x;
    if (c >= N) return;
    float s = bih[c];
    for (int j = 0; j < 256; ++j) s = fmaf(projb[j], W[(size_t)j * N + c], s);
    out[c] = s;
}

// outsT [t][c][b] -> outs [b][t][c]
__global__ __launch_bounds__(256) void outtr_k(const float* __restrict__ outsT,
                                               float* __restrict__ outs)
{
    int bid = blockIdx.x;
    int t = bid / 7, ct = bid % 7;
    int c0 = ct * 64, cw = (ct == 6) ? (INW - 384) : 64;
    int cwl = (cw == 64) ? 6 : 4;
    __shared__ float tile[64][65];
    int tid = threadIdx.x;
    for (int i = tid; i < cw * 64; i += 256) {
        int ci = i >> 6, bb = i & 63;
        tile[ci][bb] = outsT[((size_t)t * INW + c0 + ci) * 64 + bb];
    }
    __syncthreads();
    for (int i = tid; i < 64 * cw; i += 256) {
        int bb = i >> cwl, cc = i & (cw - 1);
        outs[((size_t)bb * TT + t) * INW + c0 + cc] = tile[cc][bb];
    }
}

// ---------------- fence-free grid barrier ----------------
// sc1 state stores are drained by the compiler's vmcnt(0) before s_barrier;
// counter is a MALL-coherent atomic. No L2 writeback/invalidate anywhere.
__device__ __forceinline__ void gridbar(unsigned* cnt, unsigned bar) {
    __syncthreads();
    if (threadIdx.x == 0) {
        asm volatile("s_waitcnt vmcnt(0)" ::: "memory");
        __hip_atomic_fetch_add(cnt, 1u, __ATOMIC_RELAXED, __HIP_MEMORY_SCOPE_AGENT);
        unsigned target = bar * (unsigned)GBLK;
        while (__hip_atomic_load(cnt, __ATOMIC_RELAXED, __HIP_MEMORY_SCOPE_AGENT) < target) {
            __builtin_amdgcn_s_sleep(1);
        }
    }
    __syncthreads();
}

__device__ __forceinline__ float tpair(unsigned u32, int d, const float* qk,
                                       const float* vn2, float acc) {
    float xa = blo(u32) + qk[d];
    float xb = bhi(u32) + qk[d + 1];
    float ra = __builtin_amdgcn_rcpf(__builtin_amdgcn_exp2f(xa) + 1.f);
    float rb = __builtin_amdgcn_rcpf(__builtin_amdgcn_exp2f(xb) + 1.f);
    acc = fmaf(vn2[d], ra, acc);
    return fmaf(vn2[d + 1], rb, acc);
}

// ---------------- persistent mega kernel ----------------
__global__ __launch_bounds__(512, 2) void mega_k(
    const ushortT* __restrict__ xgiB, const float* __restrict__ WihcT,
    const float* __restrict__ WhhT, const float* __restrict__ att_bhh,
    const float* __restrict__ F1T, const float* __restrict__ Whh1T,
    const float* __restrict__ bf1, const float* __restrict__ d1_bhh,
    const float* __restrict__ F2T, const float* __restrict__ Wih2T,
    const float* __restrict__ Whh2T, const float* __restrict__ b2c,
    const float* __restrict__ d2_bhh,
    const float* __restrict__ melT, const float* __restrict__ FMT,
    const float* __restrict__ bmc,
    const ushortT* __restrict__ WqT, const ushortT* __restrict__ pmB,
    const float* __restrict__ enc, const float* __restrict__ vn2g,
    float* __restrict__ Sh, float* __restrict__ Sc,
    float* __restrict__ S1, float* __restrict__ S2,
    float* __restrict__ outsT, float* __restrict__ aligns,
    unsigned* __restrict__ cnt)
{
    const int tid = threadIdx.x, bid = blockIdx.x;
    const int lane = tid & 63, wq = tid >> 6;
    __shared__ __align__(16) float smem[3104];
    float* part = smem;
    unsigned bar = 0;
    const int u0 = bid * 2;

    for (int t = 0; t < TT; ++t) {
        const float* hC  = Sh + (size_t)(t + 1) * SBE;  float* hN  = Sh + (size_t)(t + 2) * SBE;
        const float* cC  = Sc + (size_t)(t + 1) * SBE;  float* cN  = Sc + (size_t)(t + 2) * SBE;
        const float* h1C = S1 + (size_t)(t + 1) * SBE;  float* h1N = S1 + (size_t)(t + 2) * SBE;
        const float* h2C = S2 + (size_t)(t + 1) * SBE;  float* h2N = S2 + (size_t)(t + 2) * SBE;
        const ushortT* xgi_t = xgiB + (size_t)t * (GG * 64);

        // ===== phase 1: attention GRU. warp = (state c/h, quarter) =====
        {
            int q = wq & 3;
            const float* st = ((wq < 4) ? cC : hC) + (q * 64) * 64 + lane;
            const float* W  = (wq < 4) ? WihcT : WhhT;
            int ko = q * 64;
            float a0 = 0.f, a1 = 0.f, a2 = 0.f, a3 = 0.f, a4 = 0.f, a5 = 0.f;
            mv6(st,
                W + ((size_t)(0 * 256 + u0 + 0)) * 256 + ko,
                W + ((size_t)(0 * 256 + u0 + 1)) * 256 + ko,
                W + ((size_t)(1 * 256 + u0 + 0)) * 256 + ko,
                W + ((size_t)(1 * 256 + u0 + 1)) * 256 + ko,
                W + ((size_t)(2 * 256 + u0 + 0)) * 256 + ko,
                W + ((size_t)(2 * 256 + u0 + 1)) * 256 + ko,
                64, a0, a1, a2, a3, a4, a5);
            // part[(wq*2+u)*3+g]
            part[((wq * 2 + 0) * 3 + 0) * 64 + lane] = a0;
            part[((wq * 2 + 1) * 3 + 0) * 64 + lane] = a1;
            part[((wq * 2 + 0) * 3 + 1) * 64 + lane] = a2;
            part[((wq * 2 + 1) * 3 + 1) * 64 + lane] = a3;
            part[((wq * 2 + 0) * 3 + 2) * 64 + lane] = a4;
            part[((wq * 2 + 1) * 3 + 2) * 64 + lane] = a5;
            __syncthreads();
            if (wq < 2) {
                int uu = u0 + wq;
                float g_[6];
#pragma unroll
                for (int g = 0; g < 3; ++g) {
                    float si = 0.f, sh = 0.f;
#pragma unroll
                    for (int w = 0; w < 4; ++w) {
                        si += part[((w * 2 + wq) * 3 + g) * 64 + lane];
                        sh += part[(((w + 4) * 2 + wq) * 3 + g) * 64 + lane];
                    }
                    g_[g] = si; g_[3 + g] = sh;
                }
                float ir  = g_[0] + bf2f(xgi_t[(size_t)(0 * 256 + uu) * 64 + lane]);
                float iz  = g_[1] + bf2f(xgi_t[(size_t)(1 * 256 + uu) * 64 + lane]);
                float in_ = g_[2] + bf2f(xgi_t[(size_t)(2 * 256 + uu) * 64 + lane]);
                float hr = g_[3] + att_bhh[uu];
                float hz = g_[4] + att_bhh[256 + uu];
                float hn = g_[5] + att_bhh[512 + uu];
                float hp = hC[(size_t)uu * 64 + lane];
                stS(&hN[(size_t)uu * 64 + lane], gru_h(ir, iz, in_, hr, hz, hn, hp));
            }
        }
        gridbar(cnt, ++bar);

        // ===== phase 2: attention (blocks 0..63, one per batch) =====
        if (bid < BB) {
            const int b = bid;
            float* hsh   = smem;            // 256
            float* qk    = smem + 256;      // 256
            float* vn2   = smem + 512;      // 256
            float* ash   = smem + 768;      // 512
            float* red   = smem + 1280;     // 8 (pad to 32)
            float* cpart = smem + 1312;     // 512
            if (tid < 256) { hsh[tid] = hN[(size_t)tid * 64 + b]; vn2[tid] = vn2g[tid]; }
            __syncthreads();
            if (tid < 256) {
                const ushortT* wr = WqT + (size_t)tid * 256;
                float acc = 0.f;
                for (int k = 0; k < 256; k += 8) {
                    uint4 w = *(const uint4*)(wr + k);
                    acc = fmaf(hsh[k + 0], blo(w.x), acc); acc = fmaf(hsh[k + 1], bhi(w.x), acc);
                    acc = fmaf(hsh[k + 2], blo(w.y), acc); acc = fmaf(hsh[k + 3], bhi(w.y), acc);
                    acc = fmaf(hsh[k + 4], blo(w.z), acc); acc = fmaf(hsh[k + 5], bhi(w.z), acc);
                    acc = fmaf(hsh[k + 6], blo(w.w), acc); acc = fmaf(hsh[k + 7], bhi(w.w), acc);
                }
                qk[tid] = acc * CSC;
            }
            __syncthreads();
            const ushortT* pr = pmB + ((size_t)b * TE + tid) * 256;
            float e = 0.f;
            for (int d = 0; d < 256; d += 8) {
                uint4 w = *(const uint4*)(pr + d);
                e = tpair(w.x, d + 0, qk, vn2, e);
                e = tpair(w.y, d + 2, qk, vn2, e);
                e = tpair(w.z, d + 4, qk, vn2, e);
                e = tpair(w.w, d + 6, qk, vn2, e);
            }
            float m = e;
            for (int o = 32; o; o >>= 1) m = fmaxf(m, __shfl_xor(m, o));
            if (lane == 0) red[wq] = m;
            __syncthreads();
            m = red[0];
            for (int i = 1; i < 8; ++i) m = fmaxf(m, red[i]);
            float pe = __builtin_amdgcn_exp2f((e - m) * L2E);
            float ssum = pe;
            for (int o = 32; o; o >>= 1) ssum += __shfl_xor(ssum, o);
            __syncthreads();
            if (lane == 0) red[wq] = ssum;
            __syncthreads();
            ssum = red[0] + red[1] + red[2] + red[3] + red[4] + red[5] + red[6] + red[7];
            float a = pe * __builtin_amdgcn_rcpf(ssum);
            ash[tid] = a;
            aligns[((size_t)b * TT + t) * TE + tid] = a;
            __syncthreads();
            // ctx: thread = (d, te-half), reads enc fp32 directly (coalesced over d)
            int d = tid & 255, ph = tid >> 8;
            const float* er = enc + ((size_t)b * TE + ph * 256) * DD + d;
            const float* ap = ash + ph * 256;
            float acc = 0.f;
#pragma unroll 4
            for (int p = 0; p < 256; ++p) acc = fmaf(ap[p], er[(size_t)p * DD], acc);
            cpart[ph * 256 + d] = acc;
            __syncthreads();
            if (tid < 256) stS(&cN[(size_t)tid * 64 + b], cpart[tid] + cpart[256 + tid]);
        }
        gridbar(cnt, ++bar);

        // ===== phase 4: dec1 GRU. warps 0-3: [hN;cN] 128-slices x F1T; 4-7: h1C quarters x Whh1T =====
        {
            float a0 = 0.f, a1 = 0.f, a2 = 0.f, a3 = 0.f, a4 = 0.f, a5 = 0.f;
            if (wq < 4) {
                const float* st = ((wq < 2) ? hN : cN) + ((wq & 1) * 128) * 64 + lane;
                int ko = wq * 128;
                mv6(st,
                    F1T + ((size_t)(0 * 256 + u0 + 0)) * 512 + ko,
                    F1T + ((size_t)(0 * 256 + u0 + 1)) * 512 + ko,
                    F1T + ((size_t)(1 * 256 + u0 + 0)) * 512 + ko,
                    F1T + ((size_t)(1 * 256 + u0 + 1)) * 512 + ko,
                    F1T + ((size_t)(2 * 256 + u0 + 0)) * 512 + ko,
                    F1T + ((size_t)(2 * 256 + u0 + 1)) * 512 + ko,
                    128, a0, a1, a2, a3, a4, a5);
            } else {
                int q = wq - 4;
                const float* st = h1C + (q * 64) * 64 + lane;
                int ko = q * 64;
                mv6(st,
                    Whh1T + ((size_t)(0 * 256 + u0 + 0)) * 256 + ko,
                    Whh1T + ((size_t)(0 * 256 + u0 + 1)) * 256 + ko,
                    Whh1T + ((size_t)(1 * 256 + u0 + 0)) * 256 + ko,
                    Whh1T + ((size_t)(1 * 256 + u0 + 1)) * 256 + ko,
                    Whh1T + ((size_t)(2 * 256 + u0 + 0)) * 256 + ko,
                    Whh1T + ((size_t)(2 * 256 + u0 + 1)) * 256 + ko,
                    64, a0, a1, a2, a3, a4, a5);
            }
            part[((wq * 2 + 0) * 3 + 0) * 64 + lane] = a0;
            part[((wq * 2 + 1) * 3 + 0) * 64 + lane] = a1;
            part[((wq * 2 + 0) * 3 + 1) * 64 + lane] = a2;
            part[((wq * 2 + 1) * 3 + 1) * 64 + lane] = a3;
            part[((wq * 2 + 0) * 3 + 2) * 64 + lane] = a4;
            part[((wq * 2 + 1) * 3 + 2) * 64 + lane] = a5;
            __syncthreads();
            if (wq < 2) {
                int uu = u0 + wq;
                float ir = bf1[uu], iz = bf1[256 + uu], in_ = bf1[512 + uu];
                float hr = d1_bhh[uu], hz = d1_bhh[256 + uu], hn = d1_bhh[512 + uu];
#pragma unroll
                for (int w = 0; w < 4; ++w) {
                    ir  += part[((w * 2 + wq) * 3 + 0) * 64 + lane];
                    iz  += part[((w * 2 + wq) * 3 + 1) * 64 + lane];
                    in_ += part[((w * 2 + wq) * 3 + 2) * 64 + lane];
                    hr  += part[(((w + 4) * 2 + wq) * 3 + 0) * 64 + lane];
                    hz  += part[(((w + 4) * 2 + wq) * 3 + 1) * 64 + lane];
                    hn  += part[(((w + 4) * 2 + wq) * 3 + 2) * 64 + lane];
                }
                float hp = h1C[(size_t)uu * 64 + lane];
                stS(&h1N[(size_t)uu * 64 + lane], gru_h(ir, iz, in_, hr, hz, hn, hp));
            }
        }
        gridbar(cnt, ++bar);

        // ===== phase 5: dec2 GRU. warps: 0,1 hN | 2,3 cN (F2T); 4,5 h1N (Wih2T); 6,7 h2C (Whh2T) =====
        {
            const float* st; const float* W; int ko; size_t wstride;
            if (wq < 4)      { st = ((wq < 2) ? hN : cN) + ((wq & 1) * 128) * 64;
                               W = F2T;   ko = wq * 128;        wstride = 512; }
            else if (wq < 6) { st = h1N + ((wq & 1) * 128) * 64;
                               W = Wih2T; ko = (wq & 1) * 128;  wstride = 256; }
            else             { st = h2C + ((wq & 1) * 128) * 64;
                               W = Whh2T; ko = (wq & 1) * 128;  wstride = 256; }
            float a0 = 0.f, a1 = 0.f, a2 = 0.f, a3 = 0.f, a4 = 0.f, a5 = 0.f;
            mv6(st + lane,
                W + ((size_t)(0 * 256 + u0 + 0)) * wstride + ko,
                W + ((size_t)(0 * 256 + u0 + 1)) * wstride + ko,
                W + ((size_t)(1 * 256 + u0 + 0)) * wstride + ko,
                W + ((size_t)(1 * 256 + u0 + 1)) * wstride + ko,
                W + ((size_t)(2 * 256 + u0 + 0)) * wstride + ko,
                W + ((size_t)(2 * 256 + u0 + 1)) * wstride + ko,
                128, a0, a1, a2, a3, a4, a5);
            part[((wq * 2 + 0) * 3 + 0) * 64 + lane] = a0;
            part[((wq * 2 + 1) * 3 + 0) * 64 + lane] = a1;
            part[((wq * 2 + 0) * 3 + 1) * 64 + lane] = a2;
            part[((wq * 2 + 1) * 3 + 1) * 64 + lane] = a3;
            part[((wq * 2 + 0) * 3 + 2) * 64 + lane] = a4;
            part[((wq * 2 + 1) * 3 + 2) * 64 + lane] = a5;
            __syncthreads();
            if (wq < 2) {
                int uu = u0 + wq;
                float ir = b2c[uu], iz = b2c[256 + uu], in_ = b2c[512 + uu];
                float hr = d2_bhh[uu], hz = d2_bhh[256 + uu], hn = d2_bhh[512 + uu];
#pragma unroll
                for (int w = 0; w < 6; ++w) {
                    ir  += part[((w * 2 + wq) * 3 + 0) * 64 + lane];
                    iz  += part[((w * 2 + wq) * 3 + 1) * 64 + lane];
                    in_ += part[((w * 2 + wq) * 3 + 2) * 64 + lane];
                }
#pragma unroll
                for (int w = 6; w < 8; ++w) {
                    hr += part[((w * 2 + wq) * 3 + 0) * 64 + lane];
                    hz += part[((w * 2 + wq) * 3 + 1) * 64 + lane];
                    hn += part[((w * 2 + wq) * 3 + 2) * 64 + lane];
                }
                float hp = h2C[(size_t)uu * 64 + lane];
                stS(&h2N[(size_t)uu * 64 + lane], gru_h(ir, iz, in_, hr, hz, hn, hp));
            }
        }
        gridbar(cnt, ++bar);

        // ===== phase 6: mel out. cols c = bid + 128k. warps: 0,1 h1N | 2,3 h2N (melT); 4,5 hN | 6,7 cN (FMT) =====
        {
            int c0 = bid, half = wq & 1, ko = half * 128;
            int cA = c0,      wA = (cA < INW) ? cA : 0;
            int cB = c0+128,  wB = (cB < INW) ? cB : 0;
            int cC2 = c0+256, wC = (cC2 < INW) ? cC2 : 0;
            int cD = c0+384,  wD = (cD < INW) ? cD : 0;
            const float* st; const float* Wb; size_t wstride; int woff;
            if (wq < 2)      { st = h1N + ko * 64; Wb = melT; wstride = 256; woff = ko; }
            else if (wq < 4) { st = h2N + ko * 64; Wb = melT; wstride = 256; woff = ko; }
            else if (wq < 6) { st = hN + ko * 64;  Wb = FMT;  wstride = 512; woff = ko; }
            else             { st = cN + ko * 64;  Wb = FMT;  wstride = 512; woff = 256 + ko; }
            float a0 = 0.f, a1 = 0.f, a2 = 0.f, a3 = 0.f;
            mv4(st + lane,
                Wb + (size_t)wA * wstride + woff,
                Wb + (size_t)wB * wstride + woff,
                Wb + (size_t)wC * wstride + woff,
                Wb + (size_t)wD * wstride + woff,
                128, a0, a1, a2, a3);
            part[(wq * 4 + 0) * 64 + lane] = a0;
            part[(wq * 4 + 1) * 64 + lane] = a1;
            part[(wq * 4 + 2) * 64 + lane] = a2;
            part[(wq * 4 + 3) * 64 + lane] = a3;
            __syncthreads();
            if (wq < 4) {
                int c = c0 + 128 * wq;
                if (c < INW) {
                    float acc = bmc[c];
#pragma unroll
                    for (int w = 0; w < 8; ++w) acc += part[(w * 4 + wq) * 64 + lane];
                    outsT[((size_t)t * INW + c) * 64 + lane] = acc;
                }
            }
        }
        __syncthreads();   // protect part[] before next-step phase 1
    }
}

// ---------------- host launcher ----------------
extern "C" void kernel_launch(void* const* d_in, const int* in_sizes, int n_in,
                              void* d_out, int out_size, void* d_ws, size_t ws_size,
                              hipStream_t stream) {
    const float* enc     = (const float*)d_in[0];
    const float* mel     = (const float*)d_in[1];
    const float* pw1     = (const float*)d_in[2];
    const float* pb1     = (const float*)d_in[3];
    const float* pw2     = (const float*)d_in[4];
    const float* pb2     = (const float*)d_in[5];
    const float* att_wih = (const float*)d_in[6];
    const float* att_whh = (const float*)d_in[7];
    const float* att_bih = (const float*)d_in[8];
    const float* att_bhh = (const float*)d_in[9];
    const float* mem_w   = (const float*)d_in[10];
    const float* query_w = (const float*)d_in[11];
    const float* att_v   = (const float*)d_in[12];
    const float* proj_w  = (const float*)d_in[13];
    const float* proj_b  = (const float*)d_in[14];
    const float* d1_wih  = (const float*)d_in[15];
    const float* d1_whh  = (const float*)d_in[16];
    const float* d1_bih  = (const float*)d_in[17];
    const float* d1_bhh  = (const float*)d_in[18];
    const float* d2_wih  = (const float*)d_in[19];
    const float* d2_whh  = (const float*)d_in[20];
    const float* d2_bih  = (const float*)d_in[21];
    const float* d2_bhh  = (const float*)d_in[22];
    const float* mel_w   = (const float*)d_in[23];
    const float* mel_b   = (const float*)d_in[24];

    float* outs = (float*)d_out;
    float* aligns = outs + (size_t)BB * TT * INW;

    char* p = (char*)d_ws;
    auto take = [&](size_t bytes) -> char* {
        char* r = p;
        p += (bytes + 255) & ~(size_t)255;
        return r;
    };
    // generation-unique state buffers: Sh/Sc/S1/S2, NG gens x 64KB
    float* Sh = (float*)take((size_t)NG * SBE * 4);
    float* Sc = (float*)take((size_t)NG * SBE * 4);
    float* S1 = (float*)take((size_t)NG * SBE * 4);
    float* S2 = (float*)take((size_t)NG * SBE * 4);
    unsigned* cnt = (unsigned*)take(256);
    // union: X1+X2 during precompute, outsT during mega
    char* bufA = take((size_t)TT * INW * 64 * 4);   // 20.48MB
    float* X1 = (float*)bufA;
    float* X2 = (float*)(bufA + (size_t)BB * TT * PN1 * 4);
    float* outsT = (float*)bufA;
    ushortT* xgiB = (ushortT*)take((size_t)TT * GG * 64 * 2);
    __hip_bfloat16* pmB = (__hip_bfloat16*)take((size_t)BB * TE * DD * 2);
    float* WihcT = (float*)take((size_t)GG * 256 * 4);
    float* WhhT  = (float*)take((size_t)GG * 256 * 4);
    float* Whh1T = (float*)take((size_t)GG * 256 * 4);
    float* Whh2T = (float*)take((size_t)GG * 256 * 4);
    float* Wih2T = (float*)take((size_t)GG * 256 * 4);
    float* melT  = (float*)take((size_t)INW * 256 * 4);
    float* F1T   = (float*)take((size_t)GG * 512 * 4);
    float* F2T   = (float*)take((size_t)GG * 512 * 4);
    float* FMT   = (float*)take((size_t)INW * 512 * 4);
    __hip_bfloat16* WqT = (__hip_bfloat16*)take((size_t)256 * 256 * 2);
    float* memwS = (float*)take((size_t)DD * 256 * 4);
    float* bf1 = (float*)take(GG * 4);
    float* b2c = (float*)take(GG * 4);
    float* bmc = (float*)take(INW * 4);
    float* vn2g = (float*)take(256 * 4);

    // zero gens 0..1 of each state (step 0 reads gen 1)
    (void)hipMemsetAsync(Sh, 0, 2 * SBE * 4, stream);
    (void)hipMemsetAsync(Sc, 0, 2 * SBE * 4, stream);
    (void)hipMemsetAsync(S1, 0, 2 * SBE * 4, stream);
    (void)hipMemsetAsync(S2, 0, 2 * SBE * 4, stream);
    (void)hipMemsetAsync(cnt, 0, 256, stream);

    // weight transposes / preps
    trans_k<false><<<(256 * GG + 255) / 256, 256, 0, stream>>>(att_wih, 256, GG, 128, WihcT);
    trans_k<false><<<(256 * GG + 255) / 256, 256, 0, stream>>>(att_whh, 256, GG, 0, WhhT);
    trans_k<false><<<(256 * GG + 255) / 256, 256, 0, stream>>>(d1_whh, 256, GG, 0, Whh1T);
    trans_k<false><<<(256 * GG + 255) / 256, 256, 0, stream>>>(d2_whh, 256, GG, 0, Whh2T);
    trans_k<false><<<(256 * GG + 255) / 256, 256, 0, stream>>>(d2_wih, 256, GG, 0, Wih2T);
    trans_k<false><<<(256 * INW + 255) / 256, 256, 0, stream>>>(mel_w, 256, INW, 0, melT);
    trans_k<true><<<(256 * 256 + 255) / 256, 256, 0, stream>>>(query_w, 256, 256, 0, WqT);
    scale_k<<<(DD * 256 + 255) / 256, 256, 0, stream>>>(mem_w, memwS, DD * 256, CSC);
    vprep_k<<<1, 256, 0, stream>>>(att_v, vn2g);
    bfuse_k<<<3, 256, 0, stream>>>(d1_bih, proj_b, d1_wih, GG, bf1);
    bfuse_k<<<3, 256, 0, stream>>>(d2_bih, proj_b, d2_wih, GG, b2c);
    bfuse_k<<<2, 256, 0, stream>>>(mel_b, proj_b, mel_w, INW, bmc);

    // precompute GEMMs
    gemm_k<1, 0, true, true><<<dim3(PN1 / 64, BB * TT / 64), 256, 0, stream>>>(
        mel, pw1, pb1, X1, BB * TT, PN1, INW, INW, PN1);
    gemm_k<0, 0, true, true><<<dim3(PN2 / 64, BB * TT / 64), 256, 0, stream>>>(
        X1, pw2, pb2, X2, BB * TT, PN2, PN1, PN1, PN2);
    gemm_k<0, 1, false, true><<<dim3(GG / 64, BB * TT / 64), 256, 0, stream>>>(
        X2, att_wih, att_bih, xgiB, BB * TT, GG, PN2, PN2, GG);
    gemm_k<0, 2, false, false><<<dim3(DD / 64, BB * TE / 64), 256, 0, stream>>>(
        enc, memwS, nullptr, pmB, BB * TE, DD, DD, DD, DD);
    gemm_k<0, 3, false, false><<<dim3(GG / 64, 512 / 64), 256, 0, stream>>>(
        proj_w, d1_wih, nullptr, F1T, 512, GG, 256, 256, GG);
    gemm_k<0, 3, false, false><<<dim3(GG / 64, 512 / 64), 256, 0, stream>>>(
        proj_w, d2_wih, nullptr, F2T, 512, GG, 256, 256, GG);
    gemm_k<0, 3, false, false><<<dim3((INW + 63) / 64, 512 / 64), 256, 0, stream>>>(
        proj_w, mel_w, nullptr, FMT, 512, INW, 256, 256, INW);

    // the whole recurrence in one persistent kernel
    mega_k<<<GBLK, 512, 0, stream>>>(
        xgiB, WihcT, WhhT, att_bhh,
        F1T, Whh1T, bf1, d1_bhh,
        F2T, Wih2T, Whh2T, b2c, d2_bhh,
        melT, FMT, bmc,
        (const ushortT*)WqT, (const ushortT*)pmB, enc, vn2g,
        Sh, Sc, S1, S2, outsT, aligns, cnt);

    // outsT [t][c][b] -> outs [b][t][c]
    outtr_k<<<TT * 7, 256, 0, stream>>>(outsT, outs);
}

// Round 5
// 17361.125 us; speedup vs baseline: 1.4231x; 1.1279x over previous
//
#include <hip/hip_runtime.h>
#include <hip/hip_bf16.h>

// ---------------- constants ----------------
#define BB   64     // batch
#define TT   200    // decoder steps
#define TE   512    // encoder positions
#define DD   256    // encoder dim / hidden
#define HH   256    // hidden
#define GG   768    // 3*H gates
#define INW  400    // mel in/out width
#define PN1  256
#define PN2  128
#define GBLK 128    // persistent grid blocks
#define NG   (TT + 2)   // state generations (gen g written at step t=g-2)
#define SBE  (HH * BB)  // one state gen, floats (16384 = 64KB)
#define CSC  2.8853900817779268f   // 2*log2(e) for tanh via exp2
#define L2E  1.4426950408889634f

typedef unsigned short ushortT;

__device__ __forceinline__ float blo(unsigned u) { return __uint_as_float(u << 16); }
__device__ __forceinline__ float bhi(unsigned u) { return __uint_as_float(u & 0xffff0000u); }
__device__ __forceinline__ float bf2f(ushortT u) { return __uint_as_float(((unsigned)u) << 16); }

__device__ __forceinline__ float sigmf_(float x) {
    return __builtin_amdgcn_rcpf(1.f + __builtin_amdgcn_exp2f(-L2E * x));
}
__device__ __forceinline__ float tanhf_(float x) {
    return 1.f - 2.f * __builtin_amdgcn_rcpf(__builtin_amdgcn_exp2f(CSC * x) + 1.f);
}
__device__ __forceinline__ float gru_h(float ir, float iz, float in_, float hr, float hz,
                                       float hn, float hp) {
    float r = sigmf_(ir + hr), z = sigmf_(iz + hz);
    float n = tanhf_(in_ + r * hn);
    return (1.f - z) * n + z * hp;
}

// state store: write-through to the coherent point (MALL); no L2 dirty lines
__device__ __forceinline__ void stS(float* p, float v) {
    __hip_atomic_store(p, v, __ATOMIC_RELAXED, __HIP_MEMORY_SCOPE_AGENT);
}

#define FMA4(acc, w4, x0, x1, x2, x3) \
    acc = fmaf(x0, w4.x, acc); acc = fmaf(x1, w4.y, acc); \
    acc = fmaf(x2, w4.z, acc); acc = fmaf(x3, w4.w, acc)

// 6-stream matvec partial: states laid out [dim][64]
template<int DIMS>
__device__ __forceinline__ void mv6(const float* __restrict__ st,
    const float* __restrict__ w0, const float* __restrict__ w1,
    const float* __restrict__ w2, const float* __restrict__ w3,
    const float* __restrict__ w4, const float* __restrict__ w5,
    float& a0, float& a1, float& a2, float& a3, float& a4, float& a5)
{
#pragma unroll 4
    for (int j = 0; j < DIMS; j += 4) {
        float x0 = st[(j + 0) * 64], x1 = st[(j + 1) * 64];
        float x2 = st[(j + 2) * 64], x3 = st[(j + 3) * 64];
        float4 w;
        w = *(const float4*)(w0 + j); FMA4(a0, w, x0, x1, x2, x3);
        w = *(const float4*)(w1 + j); FMA4(a1, w, x0, x1, x2, x3);
        w = *(const float4*)(w2 + j); FMA4(a2, w, x0, x1, x2, x3);
        w = *(const float4*)(w3 + j); FMA4(a3, w, x0, x1, x2, x3);
        w = *(const float4*)(w4 + j); FMA4(a4, w, x0, x1, x2, x3);
        w = *(const float4*)(w5 + j); FMA4(a5, w, x0, x1, x2, x3);
    }
}

template<int DIMS>
__device__ __forceinline__ void mv4(const float* __restrict__ st,
    const float* __restrict__ w0, const float* __restrict__ w1,
    const float* __restrict__ w2, const float* __restrict__ w3,
    float& a0, float& a1, float& a2, float& a3)
{
#pragma unroll 4
    for (int j = 0; j < DIMS; j += 4) {
        float x0 = st[(j + 0) * 64], x1 = st[(j + 1) * 64];
        float x2 = st[(j + 2) * 64], x3 = st[(j + 3) * 64];
        float4 w;
        w = *(const float4*)(w0 + j); FMA4(a0, w, x0, x1, x2, x3);
        w = *(const float4*)(w1 + j); FMA4(a1, w, x0, x1, x2, x3);
        w = *(const float4*)(w2 + j); FMA4(a2, w, x0, x1, x2, x3);
        w = *(const float4*)(w3 + j); FMA4(a3, w, x0, x1, x2, x3);
    }
}

// ---------------- generic tiled fp32 GEMM (precompute only) ----------------
// AMODE: 0 normal, 1 shifted-mel. SMODE: 0 fp32 rm; 1 xgi remap (bf16); 2 bf16 rm; 3 fp32 transposed
template<int AMODE, int SMODE, bool RELU, bool BIAS>
__global__ __launch_bounds__(256) void gemm_k(
    const float* __restrict__ A, const float* __restrict__ Bm,
    const float* __restrict__ bias, void* __restrict__ Cp,
    int M, int N, int K, int lda, int ldb)
{
    __shared__ __align__(16) float As[16][68];
    __shared__ __align__(16) float Bs[16][68];
    int tid = threadIdx.x;
    int m0 = blockIdx.y * 64, n0 = blockIdx.x * 64;
    int tx = tid & 15, ty = tid >> 4;
    float acc[4][4] = {};
    for (int k0 = 0; k0 < K; k0 += 16) {
        {
            int row = tid >> 2, kq = tid & 3;
            int gr = m0 + row;
            float4 a4;
            if (AMODE == 0) {
                a4 = *(const float4*)(A + (size_t)gr * lda + k0 + kq * 4);
            } else {
                int bb = gr / TT, t = gr % TT;
                if (t == 0) a4 = make_float4(0.f, 0.f, 0.f, 0.f);
                else a4 = *(const float4*)(A + ((size_t)bb * TT + (t - 1)) * INW + k0 + kq * 4);
            }
            As[kq * 4 + 0][row] = a4.x; As[kq * 4 + 1][row] = a4.y;
            As[kq * 4 + 2][row] = a4.z; As[kq * 4 + 3][row] = a4.w;
            int kk = tid >> 4, nq = tid & 15;
            int gc = n0 + nq * 4;
            float4 b4;
            if (gc + 3 < N) {
                b4 = *(const float4*)(Bm + (size_t)(k0 + kk) * ldb + gc);
            } else {
                b4.x = (gc + 0 < N) ? Bm[(size_t)(k0 + kk) * ldb + gc + 0] : 0.f;
                b4.y = (gc + 1 < N) ? Bm[(size_t)(k0 + kk) * ldb + gc + 1] : 0.f;
                b4.z = (gc + 2 < N) ? Bm[(size_t)(k0 + kk) * ldb + gc + 2] : 0.f;
                b4.w = (gc + 3 < N) ? Bm[(size_t)(k0 + kk) * ldb + gc + 3] : 0.f;
            }
            *(float4*)&Bs[kk][nq * 4] = b4;
        }
        __syncthreads();
#pragma unroll
        for (int kk = 0; kk < 16; ++kk) {
            float4 av = *(const float4*)&As[kk][ty * 4];
            float4 bv = *(const float4*)&Bs[kk][tx * 4];
            acc[0][0] = fmaf(av.x, bv.x, acc[0][0]); acc[0][1] = fmaf(av.x, bv.y, acc[0][1]);
            acc[0][2] = fmaf(av.x, bv.z, acc[0][2]); acc[0][3] = fmaf(av.x, bv.w, acc[0][3]);
            acc[1][0] = fmaf(av.y, bv.x, acc[1][0]); acc[1][1] = fmaf(av.y, bv.y, acc[1][1]);
            acc[1][2] = fmaf(av.y, bv.z, acc[1][2]); acc[1][3] = fmaf(av.y, bv.w, acc[1][3]);
            acc[2][0] = fmaf(av.z, bv.x, acc[2][0]); acc[2][1] = fmaf(av.z, bv.y, acc[2][1]);
            acc[2][2] = fmaf(av.z, bv.z, acc[2][2]); acc[2][3] = fmaf(av.z, bv.w, acc[2][3]);
            acc[3][0] = fmaf(av.w, bv.x, acc[3][0]); acc[3][1] = fmaf(av.w, bv.y, acc[3][1]);
            acc[3][2] = fmaf(av.w, bv.z, acc[3][2]); acc[3][3] = fmaf(av.w, bv.w, acc[3][3]);
        }
        __syncthreads();
    }
#pragma unroll
    for (int i = 0; i < 4; ++i) {
#pragma unroll
        for (int j = 0; j < 4; ++j) {
            int r = m0 + ty * 4 + i, c = n0 + tx * 4 + j;
            if (c >= N) continue;
            float v = acc[i][j];
            if (BIAS) v += bias[c];
            if (RELU) v = fmaxf(v, 0.f);
            if (SMODE == 0) ((float*)Cp)[(size_t)r * N + c] = v;
            else if (SMODE == 1) ((__hip_bfloat16*)Cp)[((size_t)(r % TT) * GG + c) * 64 + (r / TT)] = __float2bfloat16(v);
            else if (SMODE == 2) ((__hip_bfloat16*)Cp)[(size_t)r * N + c] = __float2bfloat16(v);
            else ((float*)Cp)[(size_t)c * M + r] = v;
        }
    }
}

// ---------------- small precompute kernels ----------------
template<bool BF16>
__global__ __launch_bounds__(256) void trans_k(const float* __restrict__ in, int IR, int IC,
                                               int rowoff, void* __restrict__ out)
{
    int idx = blockIdx.x * 256 + threadIdx.x;
    if (idx >= IR * IC) return;
    int c = idx / IR, r = idx % IR;
    float v = in[(size_t)(r + rowoff) * IC + c];
    if (BF16) ((__hip_bfloat16*)out)[idx] = __float2bfloat16(v);
    else ((float*)out)[idx] = v;
}

__global__ __launch_bounds__(256) void scale_k(const float* __restrict__ in,
                                               float* __restrict__ out, int n, float s)
{
    int i = blockIdx.x * 256 + threadIdx.x;
    if (i < n) out[i] = in[i] * s;
}

__global__ __launch_bounds__(256) void vprep_k(const float* __restrict__ v,
                                               float* __restrict__ vn2)
{
    int i = threadIdx.x;
    if (i < 256) vn2[i] = -2.f * v[i];
}

// out[c] = bih[c] + sum_j projb[j] * W[j*N + c]
__global__ __launch_bounds__(256) void bfuse_k(const float* __restrict__ bih,
                                               const float* __restrict__ projb,
                                               const float* __restrict__ W, int N,
                                               float* __restrict__ out)
{
    int c = blockIdx.x * 256 + threadIdx.x;
    if (c >= N) return;
    float s = bih[c];
    for (int j = 0; j < 256; ++j) s = fmaf(projb[j], W[(size_t)j * N + c], s);
    out[c] = s;
}

// enc [b][p][d] fp32 -> encT [b][d][p] bf16, LDS-tiled
__global__ __launch_bounds__(256) void enct_k(const float* __restrict__ enc,
                                              ushortT* __restrict__ encT)
{
    int bid = blockIdx.x;
    int b = bid >> 6, pt = (bid >> 3) & 7, dt = bid & 7;
    int p0 = pt * 64, d0 = dt * 32;
    __shared__ ushortT tl[64][34];
    int tid = threadIdx.x;
    for (int i = tid; i < 64 * 32; i += 256) {
        int dd = i & 31, pp = i >> 5;
        float v = enc[((size_t)b * TE + p0 + pp) * DD + d0 + dd];
        tl[pp][dd] = (ushortT)(__bfloat16_as_ushort(__float2bfloat16(v)));
    }
    __syncthreads();
    for (int i = tid; i < 32 * 64; i += 256) {
        int pp = i & 63, dd = i >> 6;
        encT[((size_t)b * DD + d0 + dd) * TE + p0 + pp] = tl[pp][dd];
    }
}

// outsT [t][c][b] -> outs [b][t][c]
__global__ __launch_bounds__(256) void outtr_k(const float* __restrict__ outsT,
                                               float* __restrict__ outs)
{
    int bid = blockIdx.x;
    int t = bid / 7, ct = bid % 7;
    int c0 = ct * 64, cw = (ct == 6) ? (INW - 384) : 64;
    int cwl = (cw == 64) ? 6 : 4;
    __shared__ float tile[64][65];
    int tid = threadIdx.x;
    for (int i = tid; i < cw * 64; i += 256) {
        int ci = i >> 6, bb = i & 63;
        tile[ci][bb] = outsT[((size_t)t * INW + c0 + ci) * 64 + bb];
    }
    __syncthreads();
    for (int i = tid; i < 64 * cw; i += 256) {
        int bb = i >> cwl, cc = i & (cw - 1);
        outs[((size_t)bb * TT + t) * INW + c0 + cc] = tile[cc][bb];
    }
}

// ---------------- fence-free grid barrier ----------------
__device__ __forceinline__ void gridbar(unsigned* cnt, unsigned bar) {
    __syncthreads();
    if (threadIdx.x == 0) {
        asm volatile("s_waitcnt vmcnt(0)" ::: "memory");
        __hip_atomic_fetch_add(cnt, 1u, __ATOMIC_RELAXED, __HIP_MEMORY_SCOPE_AGENT);
        unsigned target = bar * (unsigned)GBLK;
        while (__hip_atomic_load(cnt, __ATOMIC_RELAXED, __HIP_MEMORY_SCOPE_AGENT) < target) {
            __builtin_amdgcn_s_sleep(1);
        }
    }
    __syncthreads();
}

__device__ __forceinline__ float tpair(unsigned u32, int d, const float* qk,
                                       const float* vn2, float acc) {
    float xa = blo(u32) + qk[d];
    float xb = bhi(u32) + qk[d + 1];
    float ra = __builtin_amdgcn_rcpf(__builtin_amdgcn_exp2f(xa) + 1.f);
    float rb = __builtin_amdgcn_rcpf(__builtin_amdgcn_exp2f(xb) + 1.f);
    acc = fmaf(vn2[d], ra, acc);
    return fmaf(vn2[d + 1], rb, acc);
}

// ---------------- persistent mega kernel ----------------
__global__ __launch_bounds__(512) void mega_k(
    const ushortT* __restrict__ xgiB, const float* __restrict__ WihcT,
    const float* __restrict__ WhhT, const float* __restrict__ att_bhh,
    const float* __restrict__ F1T, const float* __restrict__ Whh1T,
    const float* __restrict__ bf1, const float* __restrict__ d1_bhh,
    const float* __restrict__ F2T, const float* __restrict__ Wih2T,
    const float* __restrict__ Whh2T, const float* __restrict__ b2c,
    const float* __restrict__ d2_bhh,
    const float* __restrict__ melT, const float* __restrict__ FMT,
    const float* __restrict__ bmc,
    const ushortT* __restrict__ WqT, const ushortT* __restrict__ pmB,
    const ushortT* __restrict__ encT, const float* __restrict__ vn2g,
    float* __restrict__ Sh, float* __restrict__ Sc,
    float* __restrict__ S1, float* __restrict__ S2,
    float* __restrict__ outsT, float* __restrict__ aligns,
    unsigned* __restrict__ cnt)
{
    const int tid = threadIdx.x, bid = blockIdx.x;
    const int lane = tid & 63, wq = tid >> 6;
    __shared__ __align__(16) float smem[3104];
    float* part = smem;          // P1: rows 0..23 ; P4/P5: rows 0..47
    float* partB = smem + 1536;  // P6: 16 rows
    unsigned bar = 0;
    const int u0 = bid * 2;

    for (int t = 0; t < TT; ++t) {
        const float* hC  = Sh + (size_t)(t + 1) * SBE;  float* hN  = Sh + (size_t)(t + 2) * SBE;
        const float* cC  = Sc + (size_t)(t + 1) * SBE;  float* cN  = Sc + (size_t)(t + 2) * SBE;
        const float* h1C = S1 + (size_t)(t + 1) * SBE;  float* h1N = S1 + (size_t)(t + 2) * SBE;
        const float* h2C = S2 + (size_t)(t + 1) * SBE;  float* h2N = S2 + (size_t)(t + 2) * SBE;
        const ushortT* xgi_t = xgiB + (size_t)t * (GG * 64);

        // ===== phase A: attention GRU (warps 0-3)  ||  mel-out of step t-1 (warps 4-7) =====
        {
            if (wq < 4) {
                int role = wq >> 1, kh = wq & 1;       // role 0: ih(cC), 1: hh(hC)
                const float* st = (role ? hC : cC) + (kh * 128) * 64 + lane;
                const float* W = role ? WhhT : WihcT;
                int ko = kh * 128;
                float a0 = 0.f, a1 = 0.f, a2 = 0.f, a3 = 0.f, a4 = 0.f, a5 = 0.f;
                mv6<128>(st,
                    W + ((size_t)(0 * 256 + u0 + 0)) * 256 + ko,
                    W + ((size_t)(0 * 256 + u0 + 1)) * 256 + ko,
                    W + ((size_t)(1 * 256 + u0 + 0)) * 256 + ko,
                    W + ((size_t)(1 * 256 + u0 + 1)) * 256 + ko,
                    W + ((size_t)(2 * 256 + u0 + 0)) * 256 + ko,
                    W + ((size_t)(2 * 256 + u0 + 1)) * 256 + ko,
                    a0, a1, a2, a3, a4, a5);
                part[((wq * 2 + 0) * 3 + 0) * 64 + lane] = a0;
                part[((wq * 2 + 1) * 3 + 0) * 64 + lane] = a1;
                part[((wq * 2 + 0) * 3 + 1) * 64 + lane] = a2;
                part[((wq * 2 + 1) * 3 + 1) * 64 + lane] = a3;
                part[((wq * 2 + 0) * 3 + 2) * 64 + lane] = a4;
                part[((wq * 2 + 1) * 3 + 2) * 64 + lane] = a5;
            } else if (bid < 100 && t > 0) {
                // P6(t-1): out = melT·(h1C + h2C... separate streams) + FMT·[hC;cC]
                int c0 = bid * 4;
                const float* st; const float* Wb; size_t ws; int woff;
                if (wq == 4)      { st = h1C; Wb = melT; ws = 256; woff = 0; }
                else if (wq == 5) { st = h2C; Wb = melT; ws = 256; woff = 0; }
                else if (wq == 6) { st = hC;  Wb = FMT;  ws = 512; woff = 0; }
                else              { st = cC;  Wb = FMT;  ws = 512; woff = 256; }
                float a0 = 0.f, a1 = 0.f, a2 = 0.f, a3 = 0.f;
                mv4<256>(st + lane,
                    Wb + (size_t)(c0 + 0) * ws + woff,
                    Wb + (size_t)(c0 + 1) * ws + woff,
                    Wb + (size_t)(c0 + 2) * ws + woff,
                    Wb + (size_t)(c0 + 3) * ws + woff,
                    a0, a1, a2, a3);
                partB[((wq - 4) * 4 + 0) * 64 + lane] = a0;
                partB[((wq - 4) * 4 + 1) * 64 + lane] = a1;
                partB[((wq - 4) * 4 + 2) * 64 + lane] = a2;
                partB[((wq - 4) * 4 + 3) * 64 + lane] = a3;
            }
            __syncthreads();
            if (wq < 2) {
                int uu = u0 + wq;
                float ir  = part[((0 * 2 + wq) * 3 + 0) * 64 + lane] + part[((1 * 2 + wq) * 3 + 0) * 64 + lane]
                          + bf2f(xgi_t[(size_t)(0 * 256 + uu) * 64 + lane]);
                float iz  = part[((0 * 2 + wq) * 3 + 1) * 64 + lane] + part[((1 * 2 + wq) * 3 + 1) * 64 + lane]
                          + bf2f(xgi_t[(size_t)(1 * 256 + uu) * 64 + lane]);
                float in_ = part[((0 * 2 + wq) * 3 + 2) * 64 + lane] + part[((1 * 2 + wq) * 3 + 2) * 64 + lane]
                          + bf2f(xgi_t[(size_t)(2 * 256 + uu) * 64 + lane]);
                float hr  = part[((2 * 2 + wq) * 3 + 0) * 64 + lane] + part[((3 * 2 + wq) * 3 + 0) * 64 + lane] + att_bhh[uu];
                float hz  = part[((2 * 2 + wq) * 3 + 1) * 64 + lane] + part[((3 * 2 + wq) * 3 + 1) * 64 + lane] + att_bhh[256 + uu];
                float hn  = part[((2 * 2 + wq) * 3 + 2) * 64 + lane] + part[((3 * 2 + wq) * 3 + 2) * 64 + lane] + att_bhh[512 + uu];
                float hp  = hC[(size_t)uu * 64 + lane];
                stS(&hN[(size_t)uu * 64 + lane], gru_h(ir, iz, in_, hr, hz, hn, hp));
            }
            if (wq >= 4 && bid < 100 && t > 0) {
                int col = wq - 4, c = bid * 4 + col;
                float acc = bmc[c];
#pragma unroll
                for (int w = 0; w < 4; ++w) acc += partB[(w * 4 + col) * 64 + lane];
                outsT[((size_t)(t - 1) * INW + c) * 64 + lane] = acc;
            }
        }
        gridbar(cnt, ++bar);

        // ===== phase B: attention (blocks 0..63, one per batch) =====
        if (bid < BB) {
            const int b = bid;
            float* hsh   = smem;            // 256
            float* qk    = smem + 256;      // 256
            float* vn2   = smem + 512;      // 256
            float* ash   = smem + 768;      // 512
            float* red   = smem + 1280;     // 32
            float* cpart = smem + 1312;     // 512
            if (tid < 256) { hsh[tid] = hN[(size_t)tid * 64 + b]; vn2[tid] = vn2g[tid]; }
            __syncthreads();
            if (tid < 256) {
                const ushortT* wr = WqT + (size_t)tid * 256;
                float acc = 0.f;
#pragma unroll
                for (int k = 0; k < 256; k += 8) {
                    uint4 w = *(const uint4*)(wr + k);
                    acc = fmaf(hsh[k + 0], blo(w.x), acc); acc = fmaf(hsh[k + 1], bhi(w.x), acc);
                    acc = fmaf(hsh[k + 2], blo(w.y), acc); acc = fmaf(hsh[k + 3], bhi(w.y), acc);
                    acc = fmaf(hsh[k + 4], blo(w.z), acc); acc = fmaf(hsh[k + 5], bhi(w.z), acc);
                    acc = fmaf(hsh[k + 6], blo(w.w), acc); acc = fmaf(hsh[k + 7], bhi(w.w), acc);
                }
                qk[tid] = acc * CSC;
            }
            __syncthreads();
            const ushortT* pr = pmB + ((size_t)b * TE + tid) * 256;
            float e = 0.f;
#pragma unroll 8
            for (int d = 0; d < 256; d += 8) {
                uint4 w = *(const uint4*)(pr + d);
                e = tpair(w.x, d + 0, qk, vn2, e);
                e = tpair(w.y, d + 2, qk, vn2, e);
                e = tpair(w.z, d + 4, qk, vn2, e);
                e = tpair(w.w, d + 6, qk, vn2, e);
            }
            float m = e;
            for (int o = 32; o; o >>= 1) m = fmaxf(m, __shfl_xor(m, o));
            if (lane == 0) red[wq] = m;
            __syncthreads();
            m = red[0];
            for (int i = 1; i < 8; ++i) m = fmaxf(m, red[i]);
            float pe = __builtin_amdgcn_exp2f((e - m) * L2E);
            float ssum = pe;
            for (int o = 32; o; o >>= 1) ssum += __shfl_xor(ssum, o);
            __syncthreads();
            if (lane == 0) red[wq] = ssum;
            __syncthreads();
            ssum = red[0] + red[1] + red[2] + red[3] + red[4] + red[5] + red[6] + red[7];
            float a = pe * __builtin_amdgcn_rcpf(ssum);
            ash[tid] = a;
            aligns[((size_t)b * TT + t) * TE + tid] = a;
            __syncthreads();
            // ctx: thread = (d, te-half); encT bf16 contiguous along p -> deep MLP
            int d = tid & 255, ph = tid >> 8;
            const ushortT* er = encT + ((size_t)(b * DD + d)) * TE + ph * 256;
            const float* ap = ash + ph * 256;
            float acc = 0.f;
#pragma unroll
            for (int p = 0; p < 256; p += 8) {
                uint4 w = *(const uint4*)(er + p);
                acc = fmaf(ap[p + 0], blo(w.x), acc); acc = fmaf(ap[p + 1], bhi(w.x), acc);
                acc = fmaf(ap[p + 2], blo(w.y), acc); acc = fmaf(ap[p + 3], bhi(w.y), acc);
                acc = fmaf(ap[p + 4], blo(w.z), acc); acc = fmaf(ap[p + 5], bhi(w.z), acc);
                acc = fmaf(ap[p + 6], blo(w.w), acc); acc = fmaf(ap[p + 7], bhi(w.w), acc);
            }
            cpart[ph * 256 + d] = acc;
            __syncthreads();
            if (tid < 256) stS(&cN[(size_t)tid * 64 + b], cpart[tid] + cpart[256 + tid]);
        }
        gridbar(cnt, ++bar);

        // ===== phase C: dec1 GRU. warps 0-3: [hN;cN] x F1T; 4-7: h1C quarters x Whh1T =====
        {
            float a0 = 0.f, a1 = 0.f, a2 = 0.f, a3 = 0.f, a4 = 0.f, a5 = 0.f;
            if (wq < 4) {
                const float* st = ((wq < 2) ? hN : cN) + ((wq & 1) * 128) * 64 + lane;
                int ko = wq * 128;
                mv6<128>(st,
                    F1T + ((size_t)(0 * 256 + u0 + 0)) * 512 + ko,
                    F1T + ((size_t)(0 * 256 + u0 + 1)) * 512 + ko,
                    F1T + ((size_t)(1 * 256 + u0 + 0)) * 512 + ko,
                    F1T + ((size_t)(1 * 256 + u0 + 1)) * 512 + ko,
                    F1T + ((size_t)(2 * 256 + u0 + 0)) * 512 + ko,
                    F1T + ((size_t)(2 * 256 + u0 + 1)) * 512 + ko,
                    a0, a1, a2, a3, a4, a5);
            } else {
                int q = wq - 4;
                const float* st = h1C + (q * 64) * 64 + lane;
                int ko = q * 64;
                mv6<64>(st,
                    Whh1T + ((size_t)(0 * 256 + u0 + 0)) * 256 + ko,
                    Whh1T + ((size_t)(0 * 256 + u0 + 1)) * 256 + ko,
                    Whh1T + ((size_t)(1 * 256 + u0 + 0)) * 256 + ko,
                    Whh1T + ((size_t)(1 * 256 + u0 + 1)) * 256 + ko,
                    Whh1T + ((size_t)(2 * 256 + u0 + 0)) * 256 + ko,
                    Whh1T + ((size_t)(2 * 256 + u0 + 1)) * 256 + ko,
                    a0, a1, a2, a3, a4, a5);
            }
            part[((wq * 2 + 0) * 3 + 0) * 64 + lane] = a0;
            part[((wq * 2 + 1) * 3 + 0) * 64 + lane] = a1;
            part[((wq * 2 + 0) * 3 + 1) * 64 + lane] = a2;
            part[((wq * 2 + 1) * 3 + 1) * 64 + lane] = a3;
            part[((wq * 2 + 0) * 3 + 2) * 64 + lane] = a4;
            part[((wq * 2 + 1) * 3 + 2) * 64 + lane] = a5;
            __syncthreads();
            if (wq < 2) {
                int uu = u0 + wq;
                float ir = bf1[uu], iz = bf1[256 + uu], in_ = bf1[512 + uu];
                float hr = d1_bhh[uu], hz = d1_bhh[256 + uu], hn = d1_bhh[512 + uu];
#pragma unroll
                for (int w = 0; w < 4; ++w) {
                    ir  += part[((w * 2 + wq) * 3 + 0) * 64 + lane];
                    iz  += part[((w * 2 + wq) * 3 + 1) * 64 + lane];
                    in_ += part[((w * 2 + wq) * 3 + 2) * 64 + lane];
                    hr  += part[(((w + 4) * 2 + wq) * 3 + 0) * 64 + lane];
                    hz  += part[(((w + 4) * 2 + wq) * 3 + 1) * 64 + lane];
                    hn  += part[(((w + 4) * 2 + wq) * 3 + 2) * 64 + lane];
                }
                float hp = h1C[(size_t)uu * 64 + lane];
                stS(&h1N[(size_t)uu * 64 + lane], gru_h(ir, iz, in_, hr, hz, hn, hp));
            }
        }
        gridbar(cnt, ++bar);

        // ===== phase D: dec2 GRU. warps 0-3: [hN;cN] x F2T; 4,5: h1N x Wih2T; 6,7: h2C x Whh2T =====
        {
            const float* st; const float* W; int ko; size_t wstride;
            if (wq < 4)      { st = ((wq < 2) ? hN : cN) + ((wq & 1) * 128) * 64;
                               W = F2T;   ko = wq * 128;        wstride = 512; }
            else if (wq < 6) { st = h1N + ((wq & 1) * 128) * 64;
                               W = Wih2T; ko = (wq & 1) * 128;  wstride = 256; }
            else             { st = h2C + ((wq & 1) * 128) * 64;
                               W = Whh2T; ko = (wq & 1) * 128;  wstride = 256; }
            float a0 = 0.f, a1 = 0.f, a2 = 0.f, a3 = 0.f, a4 = 0.f, a5 = 0.f;
            mv6<128>(st + lane,
                W + ((size_t)(0 * 256 + u0 + 0)) * wstride + ko,
                W + ((size_t)(0 * 256 + u0 + 1)) * wstride + ko,
                W + ((size_t)(1 * 256 + u0 + 0)) * wstride + ko,
                W + ((size_t)(1 * 256 + u0 + 1)) * wstride + ko,
                W + ((size_t)(2 * 256 + u0 + 0)) * wstride + ko,
                W + ((size_t)(2 * 256 + u0 + 1)) * wstride + ko,
                a0, a1, a2, a3, a4, a5);
            part[((wq * 2 + 0) * 3 + 0) * 64 + lane] = a0;
            part[((wq * 2 + 1) * 3 + 0) * 64 + lane] = a1;
            part[((wq * 2 + 0) * 3 + 1) * 64 + lane] = a2;
            part[((wq * 2 + 1) * 3 + 1) * 64 + lane] = a3;
            part[((wq * 2 + 0) * 3 + 2) * 64 + lane] = a4;
            part[((wq * 2 + 1) * 3 + 2) * 64 + lane] = a5;
            __syncthreads();
            if (wq < 2) {
                int uu = u0 + wq;
                float ir = b2c[uu], iz = b2c[256 + uu], in_ = b2c[512 + uu];
                float hr = d2_bhh[uu], hz = d2_bhh[256 + uu], hn = d2_bhh[512 + uu];
#pragma unroll
                for (int w = 0; w < 6; ++w) {
                    ir  += part[((w * 2 + wq) * 3 + 0) * 64 + lane];
                    iz  += part[((w * 2 + wq) * 3 + 1) * 64 + lane];
                    in_ += part[((w * 2 + wq) * 3 + 2) * 64 + lane];
                }
#pragma unroll
                for (int w = 6; w < 8; ++w) {
                    hr += part[((w * 2 + wq) * 3 + 0) * 64 + lane];
                    hz += part[((w * 2 + wq) * 3 + 1) * 64 + lane];
                    hn += part[((w * 2 + wq) * 3 + 2) * 64 + lane];
                }
                float hp = h2C[(size_t)uu * 64 + lane];
                stS(&h2N[(size_t)uu * 64 + lane], gru_h(ir, iz, in_, hr, hz, hn, hp));
            }
        }
        gridbar(cnt, ++bar);
    }

    // ===== final mel-out for t = TT-1 (states gen TT+1) =====
    if (bid < 100) {
        const float* hF  = Sh + (size_t)(TT + 1) * SBE;
        const float* cF  = Sc + (size_t)(TT + 1) * SBE;
        const float* h1F = S1 + (size_t)(TT + 1) * SBE;
        const float* h2F = S2 + (size_t)(TT + 1) * SBE;
        if (wq >= 4) {
            int c0 = bid * 4;
            const float* st; const float* Wb; size_t ws; int woff;
            if (wq == 4)      { st = h1F; Wb = melT; ws = 256; woff = 0; }
            else if (wq == 5) { st = h2F; Wb = melT; ws = 256; woff = 0; }
            else if (wq == 6) { st = hF;  Wb = FMT;  ws = 512; woff = 0; }
            else              { st = cF;  Wb = FMT;  ws = 512; woff = 256; }
            float a0 = 0.f, a1 = 0.f, a2 = 0.f, a3 = 0.f;
            mv4<256>(st + lane,
                Wb + (size_t)(c0 + 0) * ws + woff,
                Wb + (size_t)(c0 + 1) * ws + woff,
                Wb + (size_t)(c0 + 2) * ws + woff,
                Wb + (size_t)(c0 + 3) * ws + woff,
                a0, a1, a2, a3);
            partB[((wq - 4) * 4 + 0) * 64 + lane] = a0;
            partB[((wq - 4) * 4 + 1) * 64 + lane] = a1;
            partB[((wq - 4) * 4 + 2) * 64 + lane] = a2;
            partB[((wq - 4) * 4 + 3) * 64 + lane] = a3;
        }
        __syncthreads();
        if (wq >= 4) {
            int col = wq - 4, c = bid * 4 + col;
            float acc = bmc[c];
#pragma unroll
            for (int w = 0; w < 4; ++w) acc += partB[(w * 4 + col) * 64 + lane];
            outsT[((size_t)(TT - 1) * INW + c) * 64 + lane] = acc;
        }
    }
}

// ---------------- host launcher ----------------
extern "C" void kernel_launch(void* const* d_in, const int* in_sizes, int n_in,
                              void* d_out, int out_size, void* d_ws, size_t ws_size,
                              hipStream_t stream) {
    const float* enc     = (const float*)d_in[0];
    const float* mel     = (const float*)d_in[1];
    const float* pw1     = (const float*)d_in[2];
    const float* pb1     = (const float*)d_in[3];
    const float* pw2     = (const float*)d_in[4];
    const float* pb2     = (const float*)d_in[5];
    const float* att_wih = (const float*)d_in[6];
    const float* att_whh = (const float*)d_in[7];
    const float* att_bih = (const float*)d_in[8];
    const float* att_bhh = (const float*)d_in[9];
    const float* mem_w   = (const float*)d_in[10];
    const float* query_w = (const float*)d_in[11];
    const float* att_v   = (const float*)d_in[12];
    const float* proj_w  = (const float*)d_in[13];
    const float* proj_b  = (const float*)d_in[14];
    const float* d1_wih  = (const float*)d_in[15];
    const float* d1_whh  = (const float*)d_in[16];
    const float* d1_bih  = (const float*)d_in[17];
    const float* d1_bhh  = (const float*)d_in[18];
    const float* d2_wih  = (const float*)d_in[19];
    const float* d2_whh  = (const float*)d_in[20];
    const float* d2_bih  = (const float*)d_in[21];
    const float* d2_bhh  = (const float*)d_in[22];
    const float* mel_w   = (const float*)d_in[23];
    const float* mel_b   = (const float*)d_in[24];

    float* outs = (float*)d_out;
    float* aligns = outs + (size_t)BB * TT * INW;

    char* p = (char*)d_ws;
    auto take = [&](size_t bytes) -> char* {
        char* r = p;
        p += (bytes + 255) & ~(size_t)255;
        return r;
    };
    float* Sh = (float*)take((size_t)NG * SBE * 4);
    float* Sc = (float*)take((size_t)NG * SBE * 4);
    float* S1 = (float*)take((size_t)NG * SBE * 4);
    float* S2 = (float*)take((size_t)NG * SBE * 4);
    unsigned* cnt = (unsigned*)take(256);
    char* bufA = take((size_t)TT * INW * 64 * 4);   // X1+X2 precompute / outsT mega
    float* X1 = (float*)bufA;
    float* X2 = (float*)(bufA + (size_t)BB * TT * PN1 * 4);
    float* outsT = (float*)bufA;
    ushortT* xgiB = (ushortT*)take((size_t)TT * GG * 64 * 2);
    __hip_bfloat16* pmB = (__hip_bfloat16*)take((size_t)BB * TE * DD * 2);
    ushortT* encT = (ushortT*)take((size_t)BB * TE * DD * 2);
    float* WihcT = (float*)take((size_t)GG * 256 * 4);
    float* WhhT  = (float*)take((size_t)GG * 256 * 4);
    float* Whh1T = (float*)take((size_t)GG * 256 * 4);
    float* Whh2T = (float*)take((size_t)GG * 256 * 4);
    float* Wih2T = (float*)take((size_t)GG * 256 * 4);
    float* melT  = (float*)take((size_t)INW * 256 * 4);
    float* F1T   = (float*)take((size_t)GG * 512 * 4);
    float* F2T   = (float*)take((size_t)GG * 512 * 4);
    float* FMT   = (float*)take((size_t)INW * 512 * 4);
    __hip_bfloat16* WqT = (__hip_bfloat16*)take((size_t)256 * 256 * 2);
    float* memwS = (float*)take((size_t)DD * 256 * 4);
    float* bf1 = (float*)take(GG * 4);
    float* b2c = (float*)take(GG * 4);
    float* bmc = (float*)take(INW * 4);
    float* vn2g = (float*)take(256 * 4);

    (void)hipMemsetAsync(Sh, 0, 2 * SBE * 4, stream);
    (void)hipMemsetAsync(Sc, 0, 2 * SBE * 4, stream);
    (void)hipMemsetAsync(S1, 0, 2 * SBE * 4, stream);
    (void)hipMemsetAsync(S2, 0, 2 * SBE * 4, stream);
    (void)hipMemsetAsync(cnt, 0, 256, stream);

    trans_k<false><<<(256 * GG + 255) / 256, 256, 0, stream>>>(att_wih, 256, GG, 128, WihcT);
    trans_k<false><<<(256 * GG + 255) / 256, 256, 0, stream>>>(att_whh, 256, GG, 0, WhhT);
    trans_k<false><<<(256 * GG + 255) / 256, 256, 0, stream>>>(d1_whh, 256, GG, 0, Whh1T);
    trans_k<false><<<(256 * GG + 255) / 256, 256, 0, stream>>>(d2_whh, 256, GG, 0, Whh2T);
    trans_k<false><<<(256 * GG + 255) / 256, 256, 0, stream>>>(d2_wih, 256, GG, 0, Wih2T);
    trans_k<false><<<(256 * INW + 255) / 256, 256, 0, stream>>>(mel_w, 256, INW, 0, melT);
    trans_k<true><<<(256 * 256 + 255) / 256, 256, 0, stream>>>(query_w, 256, 256, 0, WqT);
    scale_k<<<(DD * 256 + 255) / 256, 256, 0, stream>>>(mem_w, memwS, DD * 256, CSC);
    vprep_k<<<1, 256, 0, stream>>>(att_v, vn2g);
    enct_k<<<64 * 64, 256, 0, stream>>>(enc, encT);
    bfuse_k<<<3, 256, 0, stream>>>(d1_bih, proj_b, d1_wih, GG, bf1);
    bfuse_k<<<3, 256, 0, stream>>>(d2_bih, proj_b, d2_wih, GG, b2c);
    bfuse_k<<<2, 256, 0, stream>>>(mel_b, proj_b, mel_w, INW, bmc);

    gemm_k<1, 0, true, true><<<dim3(PN1 / 64, BB * TT / 64), 256, 0, stream>>>(
        mel, pw1, pb1, X1, BB * TT, PN1, INW, INW, PN1);
    gemm_k<0, 0, true, true><<<dim3(PN2 / 64, BB * TT / 64), 256, 0, stream>>>(
        X1, pw2, pb2, X2, BB * TT, PN2, PN1, PN1, PN2);
    gemm_k<0, 1, false, true><<<dim3(GG / 64, BB * TT / 64), 256, 0, stream>>>(
        X2, att_wih, att_bih, xgiB, BB * TT, GG, PN2, PN2, GG);
    gemm_k<0, 2, false, false><<<dim3(DD / 64, BB * TE / 64), 256, 0, stream>>>(
        enc, memwS, nullptr, pmB, BB * TE, DD, DD, DD, DD);
    gemm_k<0, 3, false, false><<<dim3(GG / 64, 512 / 64), 256, 0, stream>>>(
        proj_w, d1_wih, nullptr, F1T, 512, GG, 256, 256, GG);
    gemm_k<0, 3, false, false><<<dim3(GG / 64, 512 / 64), 256, 0, stream>>>(
        proj_w, d2_wih, nullptr, F2T, 512, GG, 256, 256, GG);
    gemm_k<0, 3, false, false><<<dim3((INW + 63) / 64, 512 / 64), 256, 0, stream>>>(
        proj_w, mel_w, nullptr, FMT, 512, INW, 256, 256, INW);

    mega_k<<<GBLK, 512, 0, stream>>>(
        xgiB, WihcT, WhhT, att_bhh,
        F1T, Whh1T, bf1, d1_bhh,
        F2T, Wih2T, Whh2T, b2c, d2_bhh,
        melT, FMT, bmc,
        (const ushortT*)WqT, (const ushortT*)pmB, encT, vn2g,
        Sh, Sc, S1, S2, outsT, aligns, cnt);

    outtr_k<<<TT * 7, 256, 0, stream>>>(outsT, outs);
}